// Round 11
// baseline (813.903 us; speedup 1.0000x reference)
//
#include <hip/hip_runtime.h>
#include <hip/hip_bf16.h>
#include <hip/hip_cooperative_groups.h>
#include <math.h>

namespace cg = cooperative_groups;

#define EPB  32    // edges per (virtual) block
#define MSTR 136   // m LDS row stride (shorts): 128 + 8 pad
#define FSTR 264   // node-kernel f stride

typedef __attribute__((ext_vector_type(8))) short short8;
typedef __attribute__((ext_vector_type(4))) float f32x4;

__device__ __forceinline__ unsigned short f2bf(float x) {
    unsigned int u = __float_as_uint(x);
    u += 0x7fffu + ((u >> 16) & 1u);   // round-to-nearest-even
    return (unsigned short)(u >> 16);
}
__device__ __forceinline__ float bf2f(short v) {
    return __uint_as_float(((unsigned int)(unsigned short)v) << 16);
}
__device__ __forceinline__ unsigned int pkbf(float a, float b) {
    __hip_bfloat162 h = __float22bfloat162_rn(make_float2(a, b));
    union { __hip_bfloat162 h2; unsigned int u; } cv; cv.h2 = h; return cv.u;
}
__device__ __forceinline__ float frcp(float x) { return __builtin_amdgcn_rcpf(x); }
__device__ __forceinline__ float fsilu(float x) {
    return x * frcp(1.0f + __expf(-x));
}
__device__ __forceinline__ float fsigm(float x) {
    return frcp(1.0f + __expf(-x));
}
__device__ __forceinline__ void atomAddF(float* p, float v) {
    unsafeAtomicAdd(p, v);
}

struct ProjDesc { const float* A; const short* Bt; short* out; const float* bias;
                  int rows; int ktb; int co; int hasb; };

struct EdgeSet {
    const short *Ps, *Pd;        // [nodes][256] bf16: 0..127 e-proj, 128..255 c-proj (b1 in Pd)
    const float *xs, *xd;
    const int *esrc, *edst;      // dst-sorted
    const float *w256e, *w256c;  // dij coefficient rows (fp32)
    const short *W2t, *cW2t;     // [128][128] bf16 [col][k]
    const float *b2e, *b2c;
    const float *aW, *ab, *cW3;
};

// ===========================================================================
// Fallback-path kernels (R9-validated chain)
// ===========================================================================
struct PrepArgs { const float* src[10]; };

__global__ __launch_bounds__(256) void prep_hist_kernel(PrepArgs pa, short* __restrict__ wsb,
                                                        const int* __restrict__ lld,
                                                        const int* __restrict__ kld,
                                                        int* __restrict__ hist) {
    int idx = blockIdx.x * 256 + threadIdx.x;
    if (idx < 245760) {
        int pair = idx / 49152;
        int rem  = idx - pair * 49152;
        int second = (rem >= 32768) ? 1 : 0;
        int mi = pair * 2 + second;
        int within = second ? (rem - 32768) : rem;
        int n, k, K;
        if (second) { K = 128; n = within >> 7; k = within & 127; }
        else        { K = 256; n = within >> 8; k = within & 255; }
        int dstoff = pair * 49152 + second * 32768;
        wsb[dstoff + n * K + k] = (short)f2bf(pa.src[mi][k * 128 + n]);
        return;
    }
    idx -= 245760;
    if (idx < 320000) { atomicAdd(&hist[lld[idx]], 1); return; }
    idx -= 320000;
    if (idx < 160000) atomicAdd(&hist[10000 + kld[idx]], 1);
}

__global__ __launch_bounds__(256) void scan_kernel(const int* __restrict__ hist,
                                                   int* __restrict__ cursor) {
    __shared__ int bins[10000];
    __shared__ int ps[256];
    const int b = blockIdx.x, t = threadIdx.x;
    const int* h = hist + b * 10000;
    int* cur = cursor + b * 10000;
    for (int i = t; i < 10000; i += 256) bins[i] = h[i];
    __syncthreads();
    const int base = t * 40;
    int s = 0;
#pragma unroll 8
    for (int i = 0; i < 40; i++) { int ii = base + i; if (ii < 10000) s += bins[ii]; }
    ps[t] = s;
    __syncthreads();
    for (int off = 1; off < 256; off <<= 1) {
        int v = (t >= off) ? ps[t - off] : 0;
        __syncthreads();
        ps[t] += v;
        __syncthreads();
    }
    int run = ps[t] - s;
    for (int i = 0; i < 40; i++) {
        int ii = base + i;
        if (ii < 10000) { int c = bins[ii]; bins[ii] = run; run += c; }
    }
    __syncthreads();
    for (int i = t; i < 10000; i += 256) cur[i] = bins[i];
}

struct CArgs {
    const int *lls, *lld, *kls, *kld;
    int* cursor;
    int *ll_ssrc, *ll_sdst, *kl_ssrc, *kl_sdst;
    ProjDesc d[8];
};

__global__ __launch_bounds__(256) void scatter_proj_kernel(CArgs ca) {
    __shared__ __align__(16) short a_lds[64 * MSTR];
    const int t = threadIdx.x;
    if (blockIdx.x < 1875) {
        int i = blockIdx.x * 256 + t;
        if (i < 320000) {
            int d = ca.lld[i];
            int p = atomicAdd(&ca.cursor[d], 1);
            ca.ll_ssrc[p] = ca.lls[i]; ca.ll_sdst[p] = d;
        } else if (i < 480000) {
            int j = i - 320000;
            int d = ca.kld[j];
            int p = atomicAdd(&ca.cursor[10000 + d], 1);
            ca.kl_ssrc[p] = ca.kls[j]; ca.kl_sdst[p] = d;
        }
        return;
    }
    const int pb = blockIdx.x - 1875;
    const int di = pb / 157, tile = pb - di * 157;
    const ProjDesc pd = ca.d[di];
    if (tile * 64 >= pd.rows) return;
    {
        const int r = t >> 2, q = t & 3;
        const int node = tile * 64 + r;
        short* arow = a_lds + r * MSTR + q * 32;
        if (node < pd.rows) {
            const float* ap = pd.A + (size_t)node * 128 + q * 32;
#pragma unroll
            for (int i = 0; i < 4; i++) {
                float4 v0 = *(const float4*)(ap + i * 8);
                float4 v1 = *(const float4*)(ap + i * 8 + 4);
                uint4 o;
                o.x = pkbf(v0.x, v0.y); o.y = pkbf(v0.z, v0.w);
                o.z = pkbf(v1.x, v1.y); o.w = pkbf(v1.z, v1.w);
                *(uint4*)(arow + i * 8) = o;
            }
        } else {
            uint4 z = make_uint4(0, 0, 0, 0);
#pragma unroll
            for (int i = 0; i < 4; i++) *(uint4*)(arow + i * 8) = z;
        }
    }
    __syncthreads();

    const int ln = t & 63, wv = t >> 6;
    const int lrow = ln & 15, quad = ln >> 4;
    const int c0 = wv * 32 + lrow, c1 = c0 + 16;

    short8 bf0[4], bf1[4];
#pragma unroll
    for (int kt = 0; kt < 4; kt++) {
        bf0[kt] = *(const short8*)(pd.Bt + c0 * 256 + (pd.ktb + kt) * 32 + quad * 8);
        bf1[kt] = *(const short8*)(pd.Bt + c1 * 256 + (pd.ktb + kt) * 32 + quad * 8);
    }
    const float bb0 = pd.hasb ? pd.bias[c0] : 0.0f;
    const float bb1 = pd.hasb ? pd.bias[c1] : 0.0f;
#pragma unroll
    for (int mt = 0; mt < 4; mt++) {
        short8 af[4];
#pragma unroll
        for (int kt = 0; kt < 4; kt++)
            af[kt] = *(const short8*)(&a_lds[(mt * 16 + lrow) * MSTR + kt * 32 + quad * 8]);
        f32x4 a0 = {0.f, 0.f, 0.f, 0.f}, a1 = {0.f, 0.f, 0.f, 0.f};
#pragma unroll
        for (int kt = 0; kt < 4; kt++) {
            a0 = __builtin_amdgcn_mfma_f32_16x16x32_bf16(af[kt], bf0[kt], a0, 0, 0, 0);
            a1 = __builtin_amdgcn_mfma_f32_16x16x32_bf16(af[kt], bf1[kt], a1, 0, 0, 0);
        }
#pragma unroll
        for (int r = 0; r < 4; r++) {
            const int node = tile * 64 + mt * 16 + quad * 4 + r;
            if (node < pd.rows) {
                pd.out[(size_t)node * 256 + pd.co + c0] = (short)f2bf(a0[r] + bb0);
                pd.out[(size_t)node * 256 + pd.co + c1] = (short)f2bf(a1[r] + bb1);
            }
        }
    }
}

struct EdgePair { EdgeSet s[2]; int split; };

__global__ __launch_bounds__(256, 8) void edge_kernel(EdgePair ep,
                                                      float* __restrict__ hne,
                                                      float* __restrict__ xne)
{
    __shared__ __align__(16) char mbuf[EPB * MSTR * 4];
    __shared__ float sv_l[EPB];
    __shared__ float gate_l[EPB];
    __shared__ float xdf[3][EPB];
    __shared__ int   dstl[EPB];
    __shared__ float gpc[4][EPB];
    __shared__ float gpe[4][EPB];

    short* mh = (short*)mbuf;
    short* mc = (short*)(mbuf + EPB * MSTR * 2);
    float* msg = (float*)mbuf;

    const int isKL = (blockIdx.x >= ep.split) ? 1 : 0;
    const EdgeSet P = ep.s[isKL];
    const int eb = (blockIdx.x - (isKL ? ep.split : 0)) * EPB;
    const int t = threadIdx.x;

    {
        const int e = t >> 3, q = t & 7;
        const int eid = eb + e;
        const int s = P.esrc[eid], d = P.edst[eid];
        float dx = P.xs[s * 3 + 0] - P.xd[d * 3 + 0];
        float dy = P.xs[s * 3 + 1] - P.xd[d * 3 + 1];
        float dz = P.xs[s * 3 + 2] - P.xd[d * 3 + 2];
        float dd = __builtin_amdgcn_sqrtf(dx * dx + dy * dy + dz * dz);
        if (q == 0) {
            dstl[e] = d;
            float inv = frcp(dd + 1.0f);
            xdf[0][e] = dx * inv; xdf[1][e] = dy * inv; xdf[2][e] = dz * inv;
        }
        const short* psrow = P.Ps + (size_t)s * 256 + q * 16;
        const short* pdrow = P.Pd + (size_t)d * 256 + q * 16;
#pragma unroll
        for (int path = 0; path < 2; path++) {
            const short* ps = psrow + path * 128;
            const short* pq = pdrow + path * 128;
            const float* wq = (path ? P.w256c : P.w256e) + q * 16;
            short* mrow = (path ? mc : mh) + e * MSTR + q * 16;
#pragma unroll
            for (int i = 0; i < 2; i++) {
                short8 a = *(const short8*)(ps + i * 8);
                short8 b = *(const short8*)(pq + i * 8);
                float4 wA = *(const float4*)(wq + i * 8);
                float4 wB = *(const float4*)(wq + i * 8 + 4);
                float v0 = fsilu(bf2f(a[0]) + bf2f(b[0]) + dd * wA.x);
                float v1 = fsilu(bf2f(a[1]) + bf2f(b[1]) + dd * wA.y);
                float v2 = fsilu(bf2f(a[2]) + bf2f(b[2]) + dd * wA.z);
                float v3 = fsilu(bf2f(a[3]) + bf2f(b[3]) + dd * wA.w);
                float v4 = fsilu(bf2f(a[4]) + bf2f(b[4]) + dd * wB.x);
                float v5 = fsilu(bf2f(a[5]) + bf2f(b[5]) + dd * wB.y);
                float v6 = fsilu(bf2f(a[6]) + bf2f(b[6]) + dd * wB.z);
                float v7 = fsilu(bf2f(a[7]) + bf2f(b[7]) + dd * wB.w);
                uint4 o;
                o.x = pkbf(v0, v1); o.y = pkbf(v2, v3);
                o.z = pkbf(v4, v5); o.w = pkbf(v6, v7);
                *(uint4*)(mrow + i * 8) = o;
            }
        }
    }
    __syncthreads();

    const int ln = t & 63, wv = t >> 6;
    const int lrow = ln & 15, quad = ln >> 4;
    const int c0 = wv * 32 + lrow, c1 = c0 + 16;

    {
        short8 bf0[4], bf1[4];
#pragma unroll
        for (int kt = 0; kt < 4; kt++) {
            bf0[kt] = *(const short8*)(P.cW2t + c0 * 128 + kt * 32 + quad * 8);
            bf1[kt] = *(const short8*)(P.cW2t + c1 * 128 + kt * 32 + quad * 8);
        }
        const float cw0 = P.cW3[c0], cw1 = P.cW3[c1];
        const float bb0 = P.b2c[c0], bb1 = P.b2c[c1];
#pragma unroll
        for (int mt = 0; mt < 2; mt++) {
            short8 af[4];
#pragma unroll
            for (int kt = 0; kt < 4; kt++)
                af[kt] = *(const short8*)(&mc[(mt * 16 + lrow) * MSTR + kt * 32 + quad * 8]);
            f32x4 a0 = {0.f, 0.f, 0.f, 0.f}, a1 = {0.f, 0.f, 0.f, 0.f};
#pragma unroll
            for (int kt = 0; kt < 4; kt++) {
                a0 = __builtin_amdgcn_mfma_f32_16x16x32_bf16(af[kt], bf0[kt], a0, 0, 0, 0);
                a1 = __builtin_amdgcn_mfma_f32_16x16x32_bf16(af[kt], bf1[kt], a1, 0, 0, 0);
            }
#pragma unroll
            for (int r = 0; r < 4; r++) {
                float v0 = fsilu(a0[r] + bb0);
                float v1 = fsilu(a1[r] + bb1);
                float g = v0 * cw0 + v1 * cw1;
                g += __shfl_xor(g, 1, 64);
                g += __shfl_xor(g, 2, 64);
                g += __shfl_xor(g, 4, 64);
                g += __shfl_xor(g, 8, 64);
                if (lrow == 0) gpc[wv][mt * 16 + quad * 4 + r] = g;
            }
        }
    }

    float m2s[2][8];
    {
        short8 bf0[4], bf1[4];
#pragma unroll
        for (int kt = 0; kt < 4; kt++) {
            bf0[kt] = *(const short8*)(P.W2t + c0 * 128 + kt * 32 + quad * 8);
            bf1[kt] = *(const short8*)(P.W2t + c1 * 128 + kt * 32 + quad * 8);
        }
        const float aw0 = P.aW[c0], aw1 = P.aW[c1];
        const float bb0 = P.b2e[c0], bb1 = P.b2e[c1];
#pragma unroll
        for (int mt = 0; mt < 2; mt++) {
            short8 af[4];
#pragma unroll
            for (int kt = 0; kt < 4; kt++)
                af[kt] = *(const short8*)(&mh[(mt * 16 + lrow) * MSTR + kt * 32 + quad * 8]);
            f32x4 a0 = {0.f, 0.f, 0.f, 0.f}, a1 = {0.f, 0.f, 0.f, 0.f};
#pragma unroll
            for (int kt = 0; kt < 4; kt++) {
                a0 = __builtin_amdgcn_mfma_f32_16x16x32_bf16(af[kt], bf0[kt], a0, 0, 0, 0);
                a1 = __builtin_amdgcn_mfma_f32_16x16x32_bf16(af[kt], bf1[kt], a1, 0, 0, 0);
            }
#pragma unroll
            for (int r = 0; r < 4; r++) {
                float v0 = fsilu(a0[r] + bb0);
                float v1 = fsilu(a1[r] + bb1);
                m2s[mt][r] = v0; m2s[mt][4 + r] = v1;
                float g = v0 * aw0 + v1 * aw1;
                g += __shfl_xor(g, 1, 64);
                g += __shfl_xor(g, 2, 64);
                g += __shfl_xor(g, 4, 64);
                g += __shfl_xor(g, 8, 64);
                if (lrow == 0) gpe[wv][mt * 16 + quad * 4 + r] = g;
            }
        }
    }
    __syncthreads();

    if (t < EPB) {
        sv_l[t]   = gpc[0][t] + gpc[1][t] + gpc[2][t] + gpc[3][t];
        gate_l[t] = fsigm(gpe[0][t] + gpe[1][t] + gpe[2][t] + gpe[3][t] + P.ab[0]);
    }
#pragma unroll
    for (int mt = 0; mt < 2; mt++)
#pragma unroll
        for (int r = 0; r < 4; r++) {
            const int erow = mt * 16 + quad * 4 + r;
            msg[erow * 132 + c0] = m2s[mt][r];
            msg[erow * 132 + c1] = m2s[mt][4 + r];
        }
    __syncthreads();

    if (t < 128) {
        const int col = t;
        float acc = 0.0f;
        int cur = dstl[0];
#pragma unroll 4
        for (int e = 0; e < EPB; e++) {
            const int d = dstl[e];
            if (d != cur) {
                atomAddF(&hne[(size_t)cur * 128 + col], acc);
                acc = 0.0f; cur = d;
            }
            acc += msg[e * 132 + col] * gate_l[e];
        }
        atomAddF(&hne[(size_t)cur * 128 + col], acc);
    } else if (t < 131) {
        const int ax = t - 128;
        float acc = 0.0f;
        int cur = dstl[0];
        for (int e = 0; e < EPB; e++) {
            const int d = dstl[e];
            if (d != cur) {
                atomAddF(&xne[cur * 3 + ax], acc);
                acc = 0.0f; cur = d;
            }
            acc += sv_l[e] * xdf[ax][e];
        }
        atomAddF(&xne[cur * 3 + ax], acc);
    }
}

// ===========================================================================
// Cooperative mega kernel (grid-stride-safe for any grid >= 3)
// ===========================================================================
struct MegaArgs {
    const float* wsrc[10];
    short* wsb;
    const int *lls, *lld, *kls, *kld;
    int *hist, *cursor;
    int *ll_ssrc, *ll_sdst, *kl_ssrc, *kl_sdst;
    float *hne, *xne;
    ProjDesc d[8];
    EdgeSet es[2];
};

__global__ __launch_bounds__(256, 4) void mega_kernel(MegaArgs A) {
    __shared__ __align__(16) char smem[19968];
    const int t = threadIdx.x;
    const int bid = blockIdx.x;
    const int G = gridDim.x;
    cg::grid_group grid = cg::this_grid();

    // ---- stage Z: zero hne+xne (1,310,000 f) and hist (20,000 i) ----
    for (int i = bid * 256 + t; i < 1310000; i += G * 256) A.hne[i] = 0.0f;
    for (int i = bid * 256 + t; i < 20000; i += G * 256) A.hist[i] = 0;
    grid.sync();

    // ---- stage A: weight transpose + dst histogram ----
    for (int idx = bid * 256 + t; idx < 725760; idx += G * 256) {
        if (idx < 245760) {
            int pair = idx / 49152;
            int rem  = idx - pair * 49152;
            int second = (rem >= 32768) ? 1 : 0;
            int mi = pair * 2 + second;
            int within = second ? (rem - 32768) : rem;
            int n, k, K;
            if (second) { K = 128; n = within >> 7; k = within & 127; }
            else        { K = 256; n = within >> 8; k = within & 255; }
            int dstoff = pair * 49152 + second * 32768;
            A.wsb[dstoff + n * K + k] = (short)f2bf(A.wsrc[mi][k * 128 + n]);
        } else {
            int j = idx - 245760;
            if (j < 320000) atomicAdd(&A.hist[A.lld[j]], 1);
            else            atomicAdd(&A.hist[10000 + A.kld[j - 320000]], 1);
        }
    }
    grid.sync();

    // ---- stage B: scan (blocks 0,1) || proj GEMMs (blocks 2.., grid-strided) ----
    if (bid < 2) {
        int* ps = (int*)smem;
        const int* h = A.hist + bid * 10000;
        int* cur = A.cursor + bid * 10000;
        const int base = t * 40;
        int s = 0;
#pragma unroll 8
        for (int i = 0; i < 40; i++) { int ii = base + i; if (ii < 10000) s += h[ii]; }
        ps[t] = s;
        __syncthreads();
        for (int off = 1; off < 256; off <<= 1) {
            int v = (t >= off) ? ps[t - off] : 0;
            __syncthreads();
            ps[t] += v;
            __syncthreads();
        }
        int run = ps[t] - s;
        for (int i = 0; i < 40; i++) {
            int ii = base + i;
            if (ii < 10000) { cur[ii] = run; run += h[ii]; }
        }
    } else {
        short* a_lds = (short*)smem;
        for (int pb = bid - 2; pb < 1256; pb += G - 2) {
            const int di = pb / 157, tile = pb - di * 157;
            const ProjDesc pd = A.d[di];
            if (tile * 64 < pd.rows) {
                {
                    const int r = t >> 2, q = t & 3;
                    const int node = tile * 64 + r;
                    short* arow = a_lds + r * MSTR + q * 32;
                    if (node < pd.rows) {
                        const float* ap = pd.A + (size_t)node * 128 + q * 32;
#pragma unroll
                        for (int i = 0; i < 4; i++) {
                            float4 v0 = *(const float4*)(ap + i * 8);
                            float4 v1 = *(const float4*)(ap + i * 8 + 4);
                            uint4 o;
                            o.x = pkbf(v0.x, v0.y); o.y = pkbf(v0.z, v0.w);
                            o.z = pkbf(v1.x, v1.y); o.w = pkbf(v1.z, v1.w);
                            *(uint4*)(arow + i * 8) = o;
                        }
                    } else {
                        uint4 z = make_uint4(0, 0, 0, 0);
#pragma unroll
                        for (int i = 0; i < 4; i++) *(uint4*)(arow + i * 8) = z;
                    }
                }
                __syncthreads();
                const int ln = t & 63, wv = t >> 6;
                const int lrow = ln & 15, quad = ln >> 4;
                const int c0 = wv * 32 + lrow, c1 = c0 + 16;
                short8 bf0[4], bf1[4];
#pragma unroll
                for (int kt = 0; kt < 4; kt++) {
                    bf0[kt] = *(const short8*)(pd.Bt + c0 * 256 + (pd.ktb + kt) * 32 + quad * 8);
                    bf1[kt] = *(const short8*)(pd.Bt + c1 * 256 + (pd.ktb + kt) * 32 + quad * 8);
                }
                const float bb0 = pd.hasb ? pd.bias[c0] : 0.0f;
                const float bb1 = pd.hasb ? pd.bias[c1] : 0.0f;
#pragma unroll
                for (int mt = 0; mt < 4; mt++) {
                    short8 af[4];
#pragma unroll
                    for (int kt = 0; kt < 4; kt++)
                        af[kt] = *(const short8*)(&a_lds[(mt * 16 + lrow) * MSTR + kt * 32 + quad * 8]);
                    f32x4 a0 = {0.f, 0.f, 0.f, 0.f}, a1 = {0.f, 0.f, 0.f, 0.f};
#pragma unroll
                    for (int kt = 0; kt < 4; kt++) {
                        a0 = __builtin_amdgcn_mfma_f32_16x16x32_bf16(af[kt], bf0[kt], a0, 0, 0, 0);
                        a1 = __builtin_amdgcn_mfma_f32_16x16x32_bf16(af[kt], bf1[kt], a1, 0, 0, 0);
                    }
#pragma unroll
                    for (int r = 0; r < 4; r++) {
                        const int node = tile * 64 + mt * 16 + quad * 4 + r;
                        if (node < pd.rows) {
                            pd.out[(size_t)node * 256 + pd.co + c0] = (short)f2bf(a0[r] + bb0);
                            pd.out[(size_t)node * 256 + pd.co + c1] = (short)f2bf(a1[r] + bb1);
                        }
                    }
                }
            }
            __syncthreads();   // protect a_lds across iterations
        }
    }
    grid.sync();

    // ---- stage C: scatter into dst-sorted order ----
    for (int i = bid * 256 + t; i < 480000; i += G * 256) {
        if (i < 320000) {
            int d = A.lld[i];
            int p = atomicAdd(&A.cursor[d], 1);
            A.ll_ssrc[p] = A.lls[i]; A.ll_sdst[p] = d;
        } else {
            int j = i - 320000;
            int d = A.kld[j];
            int p = atomicAdd(&A.cursor[10000 + d], 1);
            A.kl_ssrc[p] = A.kls[j]; A.kl_sdst[p] = d;
        }
    }
    grid.sync();

    // ---- stage D: edges (15000 virtual blocks, grid-strided) ----
    short* mh  = (short*)smem;
    short* mc  = (short*)(smem + 8704);
    float* msg = (float*)smem;
    float* sv_l   = (float*)(smem + 17408);
    float* gate_l = (float*)(smem + 17536);
    float* xdf    = (float*)(smem + 17664);
    int*   dstl   = (int*)(smem + 18048);
    float* gpc    = (float*)(smem + 18176);
    float* gpe    = (float*)(smem + 18688);

    const int ln = t & 63, wv = t >> 6;
    const int lrow = ln & 15, quad = ln >> 4;
    const int c0 = wv * 32 + lrow, c1 = c0 + 16;

    for (int vb = bid; vb < 15000; vb += G) {
        const int isKL = (vb >= 10000) ? 1 : 0;
        const EdgeSet P = A.es[isKL];
        const int eb = (isKL ? vb - 10000 : vb) * EPB;

        {
            const int e = t >> 3, q = t & 7;
            const int eid = eb + e;
            const int s = P.esrc[eid], d = P.edst[eid];
            float dx = P.xs[s * 3 + 0] - P.xd[d * 3 + 0];
            float dy = P.xs[s * 3 + 1] - P.xd[d * 3 + 1];
            float dz = P.xs[s * 3 + 2] - P.xd[d * 3 + 2];
            float dd = __builtin_amdgcn_sqrtf(dx * dx + dy * dy + dz * dz);
            if (q == 0) {
                dstl[e] = d;
                float inv = frcp(dd + 1.0f);
                xdf[0 * EPB + e] = dx * inv;
                xdf[1 * EPB + e] = dy * inv;
                xdf[2 * EPB + e] = dz * inv;
            }
            const short* psrow = P.Ps + (size_t)s * 256 + q * 16;
            const short* pdrow = P.Pd + (size_t)d * 256 + q * 16;
#pragma unroll
            for (int path = 0; path < 2; path++) {
                const short* ps = psrow + path * 128;
                const short* pq = pdrow + path * 128;
                const float* wq = (path ? P.w256c : P.w256e) + q * 16;
                short* mrow = (path ? mc : mh) + e * MSTR + q * 16;
#pragma unroll
                for (int i = 0; i < 2; i++) {
                    short8 a = *(const short8*)(ps + i * 8);
                    short8 b = *(const short8*)(pq + i * 8);
                    float4 wA = *(const float4*)(wq + i * 8);
                    float4 wB = *(const float4*)(wq + i * 8 + 4);
                    float v0 = fsilu(bf2f(a[0]) + bf2f(b[0]) + dd * wA.x);
                    float v1 = fsilu(bf2f(a[1]) + bf2f(b[1]) + dd * wA.y);
                    float v2 = fsilu(bf2f(a[2]) + bf2f(b[2]) + dd * wA.z);
                    float v3 = fsilu(bf2f(a[3]) + bf2f(b[3]) + dd * wA.w);
                    float v4 = fsilu(bf2f(a[4]) + bf2f(b[4]) + dd * wB.x);
                    float v5 = fsilu(bf2f(a[5]) + bf2f(b[5]) + dd * wB.y);
                    float v6 = fsilu(bf2f(a[6]) + bf2f(b[6]) + dd * wB.z);
                    float v7 = fsilu(bf2f(a[7]) + bf2f(b[7]) + dd * wB.w);
                    uint4 o;
                    o.x = pkbf(v0, v1); o.y = pkbf(v2, v3);
                    o.z = pkbf(v4, v5); o.w = pkbf(v6, v7);
                    *(uint4*)(mrow + i * 8) = o;
                }
            }
        }
        __syncthreads();

        {
            short8 bf0[4], bf1[4];
#pragma unroll
            for (int kt = 0; kt < 4; kt++) {
                bf0[kt] = *(const short8*)(P.cW2t + c0 * 128 + kt * 32 + quad * 8);
                bf1[kt] = *(const short8*)(P.cW2t + c1 * 128 + kt * 32 + quad * 8);
            }
            const float cw0 = P.cW3[c0], cw1 = P.cW3[c1];
            const float bb0 = P.b2c[c0], bb1 = P.b2c[c1];
#pragma unroll
            for (int mt = 0; mt < 2; mt++) {
                short8 af[4];
#pragma unroll
                for (int kt = 0; kt < 4; kt++)
                    af[kt] = *(const short8*)(&mc[(mt * 16 + lrow) * MSTR + kt * 32 + quad * 8]);
                f32x4 a0 = {0.f, 0.f, 0.f, 0.f}, a1 = {0.f, 0.f, 0.f, 0.f};
#pragma unroll
                for (int kt = 0; kt < 4; kt++) {
                    a0 = __builtin_amdgcn_mfma_f32_16x16x32_bf16(af[kt], bf0[kt], a0, 0, 0, 0);
                    a1 = __builtin_amdgcn_mfma_f32_16x16x32_bf16(af[kt], bf1[kt], a1, 0, 0, 0);
                }
#pragma unroll
                for (int r = 0; r < 4; r++) {
                    float v0 = fsilu(a0[r] + bb0);
                    float v1 = fsilu(a1[r] + bb1);
                    float g = v0 * cw0 + v1 * cw1;
                    g += __shfl_xor(g, 1, 64);
                    g += __shfl_xor(g, 2, 64);
                    g += __shfl_xor(g, 4, 64);
                    g += __shfl_xor(g, 8, 64);
                    if (lrow == 0) gpc[wv * EPB + mt * 16 + quad * 4 + r] = g;
                }
            }
        }

        float m2s[2][8];
        {
            short8 bf0[4], bf1[4];
#pragma unroll
            for (int kt = 0; kt < 4; kt++) {
                bf0[kt] = *(const short8*)(P.W2t + c0 * 128 + kt * 32 + quad * 8);
                bf1[kt] = *(const short8*)(P.W2t + c1 * 128 + kt * 32 + quad * 8);
            }
            const float aw0 = P.aW[c0], aw1 = P.aW[c1];
            const float bb0 = P.b2e[c0], bb1 = P.b2e[c1];
#pragma unroll
            for (int mt = 0; mt < 2; mt++) {
                short8 af[4];
#pragma unroll
                for (int kt = 0; kt < 4; kt++)
                    af[kt] = *(const short8*)(&mh[(mt * 16 + lrow) * MSTR + kt * 32 + quad * 8]);
                f32x4 a0 = {0.f, 0.f, 0.f, 0.f}, a1 = {0.f, 0.f, 0.f, 0.f};
#pragma unroll
                for (int kt = 0; kt < 4; kt++) {
                    a0 = __builtin_amdgcn_mfma_f32_16x16x32_bf16(af[kt], bf0[kt], a0, 0, 0, 0);
                    a1 = __builtin_amdgcn_mfma_f32_16x16x32_bf16(af[kt], bf1[kt], a1, 0, 0, 0);
                }
#pragma unroll
                for (int r = 0; r < 4; r++) {
                    float v0 = fsilu(a0[r] + bb0);
                    float v1 = fsilu(a1[r] + bb1);
                    m2s[mt][r] = v0; m2s[mt][4 + r] = v1;
                    float g = v0 * aw0 + v1 * aw1;
                    g += __shfl_xor(g, 1, 64);
                    g += __shfl_xor(g, 2, 64);
                    g += __shfl_xor(g, 4, 64);
                    g += __shfl_xor(g, 8, 64);
                    if (lrow == 0) gpe[wv * EPB + mt * 16 + quad * 4 + r] = g;
                }
            }
        }
        __syncthreads();

        if (t < EPB) {
            sv_l[t]   = gpc[0 * EPB + t] + gpc[1 * EPB + t] + gpc[2 * EPB + t] + gpc[3 * EPB + t];
            gate_l[t] = fsigm(gpe[0 * EPB + t] + gpe[1 * EPB + t] + gpe[2 * EPB + t] + gpe[3 * EPB + t] + P.ab[0]);
        }
#pragma unroll
        for (int mt = 0; mt < 2; mt++)
#pragma unroll
            for (int r = 0; r < 4; r++) {
                const int erow = mt * 16 + quad * 4 + r;
                msg[erow * 132 + c0] = m2s[mt][r];
                msg[erow * 132 + c1] = m2s[mt][4 + r];
            }
        __syncthreads();

        if (t < 128) {
            const int col = t;
            float acc = 0.0f;
            int cur = dstl[0];
#pragma unroll 4
            for (int e = 0; e < EPB; e++) {
                const int d = dstl[e];
                if (d != cur) {
                    atomAddF(&A.hne[(size_t)cur * 128 + col], acc);
                    acc = 0.0f; cur = d;
                }
                acc += msg[e * 132 + col] * gate_l[e];
            }
            atomAddF(&A.hne[(size_t)cur * 128 + col], acc);
        } else if (t < 131) {
            const int ax = t - 128;
            float acc = 0.0f;
            int cur = dstl[0];
            for (int e = 0; e < EPB; e++) {
                const int d = dstl[e];
                if (d != cur) {
                    atomAddF(&A.xne[cur * 3 + ax], acc);
                    acc = 0.0f; cur = d;
                }
                acc += sv_l[e] * xdf[ax * EPB + e];
            }
            atomAddF(&A.xne[cur * 3 + ax], acc);
        }
        __syncthreads();
    }
}

// ---------------------------------------------------------------------------
// Node kernel: reads WS accumulators, writes d_out exactly once per element.
// ---------------------------------------------------------------------------
__global__ __launch_bounds__(256) void node_kernel(
    const float* __restrict__ h_lig, const float* __restrict__ zlig,
    const short* __restrict__ W1t, const float* __restrict__ b1v,
    const short* __restrict__ W2t, const float* __restrict__ b2v,
    const float* __restrict__ x_lig,
    const float* __restrict__ acc_h, const float* __restrict__ acc_x,
    float* __restrict__ h_out, float* __restrict__ x_out)
{
    __shared__ __align__(16) short f_lds[64 * FSTR];
    __shared__ __align__(16) short m_lds[64 * MSTR];
    const int t = threadIdx.x;
    const int nb = blockIdx.x * 64;

    {
        const int e = t >> 2, q = t & 3;
        const int node = nb + e;
        short* frow = &f_lds[e * FSTR + q * 32];
        if (node < 10000) {
            const float zi = frcp(zlig[node]);
            const float4* hp = (const float4*)(h_lig + (size_t)node * 128 + q * 32);
            const float4* np = (const float4*)(acc_h + (size_t)node * 128 + q * 32);
#pragma unroll
            for (int i = 0; i < 8; i++) {
                float4 v = hp[i];
                *(uint2*)(frow + i * 4) = make_uint2(pkbf(v.x, v.y), pkbf(v.z, v.w));
            }
#pragma unroll
            for (int i = 0; i < 8; i++) {
                float4 v = np[i];
                *(uint2*)(frow + 128 + i * 4) =
                    make_uint2(pkbf(v.x * zi, v.y * zi), pkbf(v.z * zi, v.w * zi));
            }
        } else {
            const uint2 zz = make_uint2(0, 0);
#pragma unroll
            for (int i = 0; i < 8; i++) {
                *(uint2*)(frow + i * 4) = zz;
                *(uint2*)(frow + 128 + i * 4) = zz;
            }
        }
    }
    __syncthreads();

    const int ln = t & 63, wv = t >> 6;
    const int lrow = ln & 15, quad = ln >> 4;
    const int c0 = wv * 32 + lrow, c1 = c0 + 16;

    {
        short8 bf0[8], bf1[8];
#pragma unroll
        for (int kt = 0; kt < 8; kt++) {
            bf0[kt] = *(const short8*)(W1t + c0 * 256 + kt * 32 + quad * 8);
            bf1[kt] = *(const short8*)(W1t + c1 * 256 + kt * 32 + quad * 8);
        }
        const float bb0 = b1v[c0], bb1 = b1v[c1];
#pragma unroll
        for (int mt = 0; mt < 4; mt++) {
            short8 af[8];
#pragma unroll
            for (int kt = 0; kt < 8; kt++)
                af[kt] = *(const short8*)(&f_lds[(mt * 16 + lrow) * FSTR + kt * 32 + quad * 8]);
            f32x4 a0 = {0.f, 0.f, 0.f, 0.f}, a1 = {0.f, 0.f, 0.f, 0.f};
#pragma unroll
            for (int kt = 0; kt < 8; kt++) {
                a0 = __builtin_amdgcn_mfma_f32_16x16x32_bf16(af[kt], bf0[kt], a0, 0, 0, 0);
                a1 = __builtin_amdgcn_mfma_f32_16x16x32_bf16(af[kt], bf1[kt], a1, 0, 0, 0);
            }
#pragma unroll
            for (int r = 0; r < 4; r++) {
                const int erow = mt * 16 + quad * 4 + r;
                m_lds[erow * MSTR + c0] = (short)f2bf(fsilu(a0[r] + bb0));
                m_lds[erow * MSTR + c1] = (short)f2bf(fsilu(a1[r] + bb1));
            }
        }
    }
    __syncthreads();

    {
        short8 bf0[4], bf1[4];
#pragma unroll
        for (int kt = 0; kt < 4; kt++) {
            bf0[kt] = *(const short8*)(W2t + c0 * 128 + kt * 32 + quad * 8);
            bf1[kt] = *(const short8*)(W2t + c1 * 128 + kt * 32 + quad * 8);
        }
        const float bb0 = b2v[c0], bb1 = b2v[c1];
#pragma unroll
        for (int mt = 0; mt < 4; mt++) {
            short8 af[4];
#pragma unroll
            for (int kt = 0; kt < 4; kt++)
                af[kt] = *(const short8*)(&m_lds[(mt * 16 + lrow) * MSTR + kt * 32 + quad * 8]);
            f32x4 a0 = {0.f, 0.f, 0.f, 0.f}, a1 = {0.f, 0.f, 0.f, 0.f};
#pragma unroll
            for (int kt = 0; kt < 4; kt++) {
                a0 = __builtin_amdgcn_mfma_f32_16x16x32_bf16(af[kt], bf0[kt], a0, 0, 0, 0);
                a1 = __builtin_amdgcn_mfma_f32_16x16x32_bf16(af[kt], bf1[kt], a1, 0, 0, 0);
            }
#pragma unroll
            for (int r = 0; r < 4; r++) {
                const int node = nb + mt * 16 + quad * 4 + r;
                if (node < 10000) {
                    h_out[(size_t)node * 128 + c0] = a0[r] + bb0 + h_lig[(size_t)node * 128 + c0];
                    h_out[(size_t)node * 128 + c1] = a1[r] + bb1 + h_lig[(size_t)node * 128 + c1];
                }
            }
        }
    }
    if (t < 64) {
        const int node = nb + t;
        if (node < 10000) {
            const float zi = frcp(zlig[node]);
#pragma unroll
            for (int i = 0; i < 3; i++)
                x_out[node * 3 + i] = x_lig[node * 3 + i] + acc_x[node * 3 + i] * zi;
        }
    }
}

extern "C" void kernel_launch(void* const* d_in, const int* in_sizes, int n_in,
                              void* d_out, int out_size, void* d_ws, size_t ws_size,
                              hipStream_t stream)
{
    (void)in_sizes; (void)n_in; (void)ws_size; (void)out_size;
    const float* h_lig  = (const float*)d_in[0];
    const float* h_kp   = (const float*)d_in[1];
    const float* x_lig  = (const float*)d_in[2];
    const float* x_kp   = (const float*)d_in[3];
    const float* z_lig  = (const float*)d_in[4];
    const float* ll_eW1 = (const float*)d_in[5];
    const float* ll_eb1 = (const float*)d_in[6];
    const float* ll_eW2 = (const float*)d_in[7];
    const float* ll_eb2 = (const float*)d_in[8];
    const float* ll_aW  = (const float*)d_in[9];
    const float* ll_ab  = (const float*)d_in[10];
    const float* ll_cW1 = (const float*)d_in[11];
    const float* ll_cb1 = (const float*)d_in[12];
    const float* ll_cW2 = (const float*)d_in[13];
    const float* ll_cb2 = (const float*)d_in[14];
    const float* ll_cW3 = (const float*)d_in[15];
    const float* kl_eW1 = (const float*)d_in[16];
    const float* kl_eb1 = (const float*)d_in[17];
    const float* kl_eW2 = (const float*)d_in[18];
    const float* kl_eb2 = (const float*)d_in[19];
    const float* kl_aW  = (const float*)d_in[20];
    const float* kl_ab  = (const float*)d_in[21];
    const float* kl_cW1 = (const float*)d_in[22];
    const float* kl_cb1 = (const float*)d_in[23];
    const float* kl_cW2 = (const float*)d_in[24];
    const float* kl_cb2 = (const float*)d_in[25];
    const float* kl_cW3 = (const float*)d_in[26];
    const float* n_W1   = (const float*)d_in[27];
    const float* n_b1   = (const float*)d_in[28];
    const float* n_W2   = (const float*)d_in[29];
    const float* n_b2   = (const float*)d_in[30];
    const int* ll_src = (const int*)d_in[31];
    const int* ll_dst = (const int*)d_in[32];
    const int* kl_src = (const int*)d_in[33];
    const int* kl_dst = (const int*)d_in[34];

    float* h_out = (float*)d_out;            // [10000,128]
    float* x_out = h_out + 1280000;          // [10000,3]

    // ws layout (bytes) — ~26.1 MB
    char* wsc = (char*)d_ws;
    short* wsb    = (short*)wsc;
    short* P_ll_s = (short*)(wsc +   491520);
    short* P_ll_d = (short*)(wsc +  5611520);
    short* P_kl_s = (short*)(wsc + 10731520);
    short* P_kl_d = (short*)(wsc + 11755520);
    int* ll_ssrc  = (int*)(wsc + 16875520);
    int* ll_sdst  = (int*)(wsc + 18155520);
    int* kl_ssrc  = (int*)(wsc + 19435520);
    int* kl_sdst  = (int*)(wsc + 20075520);
    int* hist     = (int*)(wsc + 20715520);
    int* cursor   = (int*)(wsc + 20795520);
    float* hne    = (float*)(wsc + 20875520);
    float* xne    = (float*)(wsc + 25995520);

    ProjDesc pdv[8];
    pdv[0] = { h_lig, wsb + 0,      P_ll_s, ll_eb1, 10000, 0, 0,   0 };
    pdv[1] = { h_lig, wsb + 49152,  P_ll_s, ll_cb1, 10000, 0, 128, 0 };
    pdv[2] = { h_lig, wsb + 0,      P_ll_d, ll_eb1, 10000, 4, 0,   1 };
    pdv[3] = { h_lig, wsb + 49152,  P_ll_d, ll_cb1, 10000, 4, 128, 1 };
    pdv[4] = { h_kp,  wsb + 98304,  P_kl_s, kl_eb1,  2000, 0, 0,   0 };
    pdv[5] = { h_kp,  wsb + 147456, P_kl_s, kl_cb1,  2000, 0, 128, 0 };
    pdv[6] = { h_lig, wsb + 98304,  P_kl_d, kl_eb1, 10000, 4, 0,   1 };
    pdv[7] = { h_lig, wsb + 147456, P_kl_d, kl_cb1, 10000, 4, 128, 1 };

    EdgeSet es0 = { P_ll_s, P_ll_d, x_lig, x_lig, ll_ssrc, ll_sdst,
                    ll_eW1 + 256 * 128, ll_cW1 + 256 * 128,
                    wsb + 32768, wsb + 81920, ll_eb2, ll_cb2,
                    ll_aW, ll_ab, ll_cW3 };
    EdgeSet es1 = { P_kl_s, P_kl_d, x_kp, x_lig, kl_ssrc, kl_sdst,
                    kl_eW1 + 256 * 128, kl_cW1 + 256 * 128,
                    wsb + 131072, wsb + 180224, kl_eb2, kl_cb2,
                    kl_aW, kl_ab, kl_cW3 };

    // ---- try cooperative mega kernel with dynamically-sized grid ----
    bool coop_ok = true;
    int cus = 0, perCU = 0;
    if (hipDeviceGetAttribute(&cus, hipDeviceAttributeMultiprocessorCount, 0) != hipSuccess
        || cus <= 0) coop_ok = false;
    if (coop_ok &&
        hipOccupancyMaxActiveBlocksPerMultiprocessor(&perCU, (const void*)mega_kernel,
                                                     256, 0) != hipSuccess) coop_ok = false;
    int grid = coop_ok ? perCU * cus : 0;
    if (grid < 3) coop_ok = false;

    if (coop_ok) {
        MegaArgs ma;
        for (int i = 0; i < 8; i++) ma.d[i] = pdv[i];
        ma.wsrc[0] = ll_eW1; ma.wsrc[1] = ll_eW2; ma.wsrc[2] = ll_cW1; ma.wsrc[3] = ll_cW2;
        ma.wsrc[4] = kl_eW1; ma.wsrc[5] = kl_eW2; ma.wsrc[6] = kl_cW1; ma.wsrc[7] = kl_cW2;
        ma.wsrc[8] = n_W1;   ma.wsrc[9] = n_W2;
        ma.wsb = wsb;
        ma.lls = ll_src; ma.lld = ll_dst; ma.kls = kl_src; ma.kld = kl_dst;
        ma.hist = hist; ma.cursor = cursor;
        ma.ll_ssrc = ll_ssrc; ma.ll_sdst = ll_sdst;
        ma.kl_ssrc = kl_ssrc; ma.kl_sdst = kl_sdst;
        ma.hne = hne; ma.xne = xne;
        ma.es[0] = es0; ma.es[1] = es1;
        void* kargs[] = { (void*)&ma };
        if (hipLaunchCooperativeKernel((void*)mega_kernel, dim3(grid), dim3(256),
                                       kargs, 0, stream) != hipSuccess) {
            coop_ok = false;
            (void)hipGetLastError();   // clear sticky error
        }
    }

    if (!coop_ok) {
        // ---- fallback: validated R9 multi-kernel chain ----
        hipMemsetAsync(hne, 0, 5240000, stream);
        hipMemsetAsync(hist, 0, 80000, stream);
        PrepArgs pa;
        pa.src[0] = ll_eW1; pa.src[1] = ll_eW2; pa.src[2] = ll_cW1; pa.src[3] = ll_cW2;
        pa.src[4] = kl_eW1; pa.src[5] = kl_eW2; pa.src[6] = kl_cW1; pa.src[7] = kl_cW2;
        pa.src[8] = n_W1;   pa.src[9] = n_W2;
        prep_hist_kernel<<<2835, 256, 0, stream>>>(pa, wsb, ll_dst, kl_dst, hist);
        scan_kernel<<<2, 256, 0, stream>>>(hist, cursor);
        CArgs ca;
        ca.lls = ll_src; ca.lld = ll_dst; ca.kls = kl_src; ca.kld = kl_dst;
        ca.cursor = cursor;
        ca.ll_ssrc = ll_ssrc; ca.ll_sdst = ll_sdst;
        ca.kl_ssrc = kl_ssrc; ca.kl_sdst = kl_sdst;
        for (int i = 0; i < 8; i++) ca.d[i] = pdv[i];
        scatter_proj_kernel<<<1875 + 8 * 157, 256, 0, stream>>>(ca);
        EdgePair ep;
        ep.split = 10000;
        ep.s[0] = es0; ep.s[1] = es1;
        edge_kernel<<<15000, 256, 0, stream>>>(ep, hne, xne);
    }

    // node MLP -> final outputs into d_out (write-once)
    node_kernel<<<157, 256, 0, stream>>>(
        h_lig, z_lig, wsb + 196608, n_b1, wsb + 229376, n_b2,
        x_lig, hne, xne, h_out, x_out);
}

// Round 12
// 410.987 us; speedup vs baseline: 1.9804x; 1.9804x over previous
//
#include <hip/hip_runtime.h>
#include <hip/hip_bf16.h>
#include <math.h>

#define EPB  32    // edges per block
#define MSTR 136   // m LDS row stride (shorts): 128 + 8 pad
#define FSTR 264   // node-kernel f stride

typedef __attribute__((ext_vector_type(8))) short short8;
typedef __attribute__((ext_vector_type(4))) float f32x4;

__device__ __forceinline__ unsigned short f2bf(float x) {
    unsigned int u = __float_as_uint(x);
    u += 0x7fffu + ((u >> 16) & 1u);   // round-to-nearest-even
    return (unsigned short)(u >> 16);
}
__device__ __forceinline__ float bf2f(short v) {
    return __uint_as_float(((unsigned int)(unsigned short)v) << 16);
}
__device__ __forceinline__ unsigned int pkbf(float a, float b) {
    __hip_bfloat162 h = __float22bfloat162_rn(make_float2(a, b));
    union { __hip_bfloat162 h2; unsigned int u; } cv; cv.h2 = h; return cv.u;
}
__device__ __forceinline__ float frcp(float x) { return __builtin_amdgcn_rcpf(x); }
__device__ __forceinline__ float fsilu(float x) {
    return x * frcp(1.0f + __expf(-x));
}
__device__ __forceinline__ float fsigm(float x) {
    return frcp(1.0f + __expf(-x));
}
__device__ __forceinline__ void atomAddF(float* p, float v) {
    unsafeAtomicAdd(p, v);   // hardware global_atomic_add_f32
}

struct ProjDesc { const float* A; const short* Bt; short* out; const float* bias;
                  int rows; int ktb; int co; int hasb; };

// ---------------------------------------------------------------------------
// Shared proj-GEMM body (virtual block pb in [0,1256))
// ---------------------------------------------------------------------------
__device__ __forceinline__ void proj_body(const ProjDesc* dv, int pb, int t, short* a_lds) {
    const int di = pb / 157, tile = pb - di * 157;
    const ProjDesc pd = dv[di];
    if (tile * 64 >= pd.rows) return;
    {
        const int r = t >> 2, q = t & 3;
        const int node = tile * 64 + r;
        short* arow = a_lds + r * MSTR + q * 32;
        if (node < pd.rows) {
            const float* ap = pd.A + (size_t)node * 128 + q * 32;
#pragma unroll
            for (int i = 0; i < 4; i++) {
                float4 v0 = *(const float4*)(ap + i * 8);
                float4 v1 = *(const float4*)(ap + i * 8 + 4);
                uint4 o;
                o.x = pkbf(v0.x, v0.y); o.y = pkbf(v0.z, v0.w);
                o.z = pkbf(v1.x, v1.y); o.w = pkbf(v1.z, v1.w);
                *(uint4*)(arow + i * 8) = o;
            }
        } else {
            uint4 z = make_uint4(0, 0, 0, 0);
#pragma unroll
            for (int i = 0; i < 4; i++) *(uint4*)(arow + i * 8) = z;
        }
    }
    __syncthreads();

    const int ln = t & 63, wv = t >> 6;
    const int lrow = ln & 15, quad = ln >> 4;
    const int c0 = wv * 32 + lrow, c1 = c0 + 16;

    short8 bf0[4], bf1[4];
#pragma unroll
    for (int kt = 0; kt < 4; kt++) {
        bf0[kt] = *(const short8*)(pd.Bt + c0 * 256 + (pd.ktb + kt) * 32 + quad * 8);
        bf1[kt] = *(const short8*)(pd.Bt + c1 * 256 + (pd.ktb + kt) * 32 + quad * 8);
    }
    const float bb0 = pd.hasb ? pd.bias[c0] : 0.0f;
    const float bb1 = pd.hasb ? pd.bias[c1] : 0.0f;
#pragma unroll
    for (int mt = 0; mt < 4; mt++) {
        short8 af[4];
#pragma unroll
        for (int kt = 0; kt < 4; kt++)
            af[kt] = *(const short8*)(&a_lds[(mt * 16 + lrow) * MSTR + kt * 32 + quad * 8]);
        f32x4 a0 = {0.f, 0.f, 0.f, 0.f}, a1 = {0.f, 0.f, 0.f, 0.f};
#pragma unroll
        for (int kt = 0; kt < 4; kt++) {
            a0 = __builtin_amdgcn_mfma_f32_16x16x32_bf16(af[kt], bf0[kt], a0, 0, 0, 0);
            a1 = __builtin_amdgcn_mfma_f32_16x16x32_bf16(af[kt], bf1[kt], a1, 0, 0, 0);
        }
#pragma unroll
        for (int r = 0; r < 4; r++) {
            const int node = tile * 64 + mt * 16 + quad * 4 + r;
            if (node < pd.rows) {
                pd.out[(size_t)node * 256 + pd.co + c0] = (short)f2bf(a0[r] + bb0);
                pd.out[(size_t)node * 256 + pd.co + c1] = (short)f2bf(a1[r] + bb1);
            }
        }
    }
}

// ---------------------------------------------------------------------------
// Kernel A: zero hne/xne + weight transpose + dst histogram (hist pre-zeroed
// by the 80KB memset dispatch).
// ---------------------------------------------------------------------------
struct PrepArgs { const float* src[10]; };

__global__ __launch_bounds__(256) void prep_hist_kernel(PrepArgs pa, short* __restrict__ wsb,
                                                        const int* __restrict__ lld,
                                                        const int* __restrict__ kld,
                                                        int* __restrict__ hist,
                                                        float* __restrict__ hne) {
    const int G = gridDim.x * 256;
    // zero accumulators (hne+xne contiguous: 1,310,000 floats)
    for (int i = blockIdx.x * 256 + threadIdx.x; i < 1310000; i += G) hne[i] = 0.0f;

    int idx = blockIdx.x * 256 + threadIdx.x;
    if (idx < 245760) {
        int pair = idx / 49152;
        int rem  = idx - pair * 49152;
        int second = (rem >= 32768) ? 1 : 0;
        int mi = pair * 2 + second;
        int within = second ? (rem - 32768) : rem;
        int n, k, K;
        if (second) { K = 128; n = within >> 7; k = within & 127; }
        else        { K = 256; n = within >> 8; k = within & 255; }
        int dstoff = pair * 49152 + second * 32768;
        wsb[dstoff + n * K + k] = (short)f2bf(pa.src[mi][k * 128 + n]);
        return;
    }
    idx -= 245760;
    if (idx < 320000) { atomicAdd(&hist[lld[idx]], 1); return; }
    idx -= 320000;
    if (idx < 160000) atomicAdd(&hist[10000 + kld[idx]], 1);
}

// ---------------------------------------------------------------------------
// Kernel B: blocks 0-1 = scan; blocks 2..629 = proj virtual blocks [0,628)
// ---------------------------------------------------------------------------
struct SPArgs { const int* hist; int* cursor; ProjDesc d[8]; };

__global__ __launch_bounds__(256) void scan_proj_kernel(SPArgs sp) {
    __shared__ __align__(16) short a_lds[64 * MSTR];   // also holds scan ps[256]
    const int t = threadIdx.x;
    if (blockIdx.x < 2) {
        int* ps = (int*)a_lds;
        const int b = blockIdx.x;
        const int* h = sp.hist + b * 10000;
        int* cur = sp.cursor + b * 10000;
        const int base = t * 40;
        int s = 0;
#pragma unroll 8
        for (int i = 0; i < 40; i++) { int ii = base + i; if (ii < 10000) s += h[ii]; }
        ps[t] = s;
        __syncthreads();
        for (int off = 1; off < 256; off <<= 1) {
            int v = (t >= off) ? ps[t - off] : 0;
            __syncthreads();
            ps[t] += v;
            __syncthreads();
        }
        int run = ps[t] - s;
        for (int i = 0; i < 40; i++) {
            int ii = base + i;
            if (ii < 10000) { cur[ii] = run; run += h[ii]; }
        }
        return;
    }
    proj_body(sp.d, blockIdx.x - 2, t, a_lds);
}

// ---------------------------------------------------------------------------
// Kernel C: blocks 0..1874 = scatter; blocks 1875.. = proj virtual [628,1256)
// ---------------------------------------------------------------------------
struct CArgs {
    const int *lls, *lld, *kls, *kld;
    int* cursor;
    int *ll_ssrc, *ll_sdst, *kl_ssrc, *kl_sdst;
    ProjDesc d[8];
};

__global__ __launch_bounds__(256) void scatter_proj_kernel(CArgs ca) {
    __shared__ __align__(16) short a_lds[64 * MSTR];
    const int t = threadIdx.x;
    if (blockIdx.x < 1875) {
        int i = blockIdx.x * 256 + t;
        if (i < 320000) {
            int d = ca.lld[i];
            int p = atomicAdd(&ca.cursor[d], 1);
            ca.ll_ssrc[p] = ca.lls[i]; ca.ll_sdst[p] = d;
        } else if (i < 480000) {
            int j = i - 320000;
            int d = ca.kld[j];
            int p = atomicAdd(&ca.cursor[10000 + d], 1);
            ca.kl_ssrc[p] = ca.kls[j]; ca.kl_sdst[p] = d;
        }
        return;
    }
    proj_body(ca.d, 628 + (blockIdx.x - 1875), t, a_lds);
}

// ---------------------------------------------------------------------------
// Edge kernel (R9-identical): EPB=32, 4 waves, 3 barriers, fast-rcp silu.
// ---------------------------------------------------------------------------
struct EdgeSet {
    const short *Ps, *Pd;
    const float *xs, *xd;
    const int *esrc, *edst;
    const float *w256e, *w256c;
    const short *W2t, *cW2t;
    const float *b2e, *b2c;
    const float *aW, *ab, *cW3;
};
struct EdgePair { EdgeSet s[2]; int split; };

__global__ __launch_bounds__(256, 8) void edge_kernel(EdgePair ep,
                                                      float* __restrict__ hne,
                                                      float* __restrict__ xne)
{
    __shared__ __align__(16) char mbuf[EPB * MSTR * 4];
    __shared__ float sv_l[EPB];
    __shared__ float gate_l[EPB];
    __shared__ float xdf[3][EPB];
    __shared__ int   dstl[EPB];
    __shared__ float gpc[4][EPB];
    __shared__ float gpe[4][EPB];

    short* mh = (short*)mbuf;
    short* mc = (short*)(mbuf + EPB * MSTR * 2);
    float* msg = (float*)mbuf;

    const int isKL = (blockIdx.x >= ep.split) ? 1 : 0;
    const EdgeSet P = ep.s[isKL];
    const int eb = (blockIdx.x - (isKL ? ep.split : 0)) * EPB;
    const int t = threadIdx.x;

    {
        const int e = t >> 3, q = t & 7;
        const int eid = eb + e;
        const int s = P.esrc[eid], d = P.edst[eid];
        float dx = P.xs[s * 3 + 0] - P.xd[d * 3 + 0];
        float dy = P.xs[s * 3 + 1] - P.xd[d * 3 + 1];
        float dz = P.xs[s * 3 + 2] - P.xd[d * 3 + 2];
        float dd = __builtin_amdgcn_sqrtf(dx * dx + dy * dy + dz * dz);
        if (q == 0) {
            dstl[e] = d;
            float inv = frcp(dd + 1.0f);
            xdf[0][e] = dx * inv; xdf[1][e] = dy * inv; xdf[2][e] = dz * inv;
        }
        const short* psrow = P.Ps + (size_t)s * 256 + q * 16;
        const short* pdrow = P.Pd + (size_t)d * 256 + q * 16;
#pragma unroll
        for (int path = 0; path < 2; path++) {
            const short* ps = psrow + path * 128;
            const short* pq = pdrow + path * 128;
            const float* wq = (path ? P.w256c : P.w256e) + q * 16;
            short* mrow = (path ? mc : mh) + e * MSTR + q * 16;
#pragma unroll
            for (int i = 0; i < 2; i++) {
                short8 a = *(const short8*)(ps + i * 8);
                short8 b = *(const short8*)(pq + i * 8);
                float4 wA = *(const float4*)(wq + i * 8);
                float4 wB = *(const float4*)(wq + i * 8 + 4);
                float v0 = fsilu(bf2f(a[0]) + bf2f(b[0]) + dd * wA.x);
                float v1 = fsilu(bf2f(a[1]) + bf2f(b[1]) + dd * wA.y);
                float v2 = fsilu(bf2f(a[2]) + bf2f(b[2]) + dd * wA.z);
                float v3 = fsilu(bf2f(a[3]) + bf2f(b[3]) + dd * wA.w);
                float v4 = fsilu(bf2f(a[4]) + bf2f(b[4]) + dd * wB.x);
                float v5 = fsilu(bf2f(a[5]) + bf2f(b[5]) + dd * wB.y);
                float v6 = fsilu(bf2f(a[6]) + bf2f(b[6]) + dd * wB.z);
                float v7 = fsilu(bf2f(a[7]) + bf2f(b[7]) + dd * wB.w);
                uint4 o;
                o.x = pkbf(v0, v1); o.y = pkbf(v2, v3);
                o.z = pkbf(v4, v5); o.w = pkbf(v6, v7);
                *(uint4*)(mrow + i * 8) = o;
            }
        }
    }
    __syncthreads();   // B1

    const int ln = t & 63, wv = t >> 6;
    const int lrow = ln & 15, quad = ln >> 4;
    const int c0 = wv * 32 + lrow, c1 = c0 + 16;

    {
        short8 bf0[4], bf1[4];
#pragma unroll
        for (int kt = 0; kt < 4; kt++) {
            bf0[kt] = *(const short8*)(P.cW2t + c0 * 128 + kt * 32 + quad * 8);
            bf1[kt] = *(const short8*)(P.cW2t + c1 * 128 + kt * 32 + quad * 8);
        }
        const float cw0 = P.cW3[c0], cw1 = P.cW3[c1];
        const float bb0 = P.b2c[c0], bb1 = P.b2c[c1];
#pragma unroll
        for (int mt = 0; mt < 2; mt++) {
            short8 af[4];
#pragma unroll
            for (int kt = 0; kt < 4; kt++)
                af[kt] = *(const short8*)(&mc[(mt * 16 + lrow) * MSTR + kt * 32 + quad * 8]);
            f32x4 a0 = {0.f, 0.f, 0.f, 0.f}, a1 = {0.f, 0.f, 0.f, 0.f};
#pragma unroll
            for (int kt = 0; kt < 4; kt++) {
                a0 = __builtin_amdgcn_mfma_f32_16x16x32_bf16(af[kt], bf0[kt], a0, 0, 0, 0);
                a1 = __builtin_amdgcn_mfma_f32_16x16x32_bf16(af[kt], bf1[kt], a1, 0, 0, 0);
            }
#pragma unroll
            for (int r = 0; r < 4; r++) {
                float v0 = fsilu(a0[r] + bb0);
                float v1 = fsilu(a1[r] + bb1);
                float g = v0 * cw0 + v1 * cw1;
                g += __shfl_xor(g, 1, 64);
                g += __shfl_xor(g, 2, 64);
                g += __shfl_xor(g, 4, 64);
                g += __shfl_xor(g, 8, 64);
                if (lrow == 0) gpc[wv][mt * 16 + quad * 4 + r] = g;
            }
        }
    }

    float m2s[2][8];
    {
        short8 bf0[4], bf1[4];
#pragma unroll
        for (int kt = 0; kt < 4; kt++) {
            bf0[kt] = *(const short8*)(P.W2t + c0 * 128 + kt * 32 + quad * 8);
            bf1[kt] = *(const short8*)(P.W2t + c1 * 128 + kt * 32 + quad * 8);
        }
        const float aw0 = P.aW[c0], aw1 = P.aW[c1];
        const float bb0 = P.b2e[c0], bb1 = P.b2e[c1];
#pragma unroll
        for (int mt = 0; mt < 2; mt++) {
            short8 af[4];
#pragma unroll
            for (int kt = 0; kt < 4; kt++)
                af[kt] = *(const short8*)(&mh[(mt * 16 + lrow) * MSTR + kt * 32 + quad * 8]);
            f32x4 a0 = {0.f, 0.f, 0.f, 0.f}, a1 = {0.f, 0.f, 0.f, 0.f};
#pragma unroll
            for (int kt = 0; kt < 4; kt++) {
                a0 = __builtin_amdgcn_mfma_f32_16x16x32_bf16(af[kt], bf0[kt], a0, 0, 0, 0);
                a1 = __builtin_amdgcn_mfma_f32_16x16x32_bf16(af[kt], bf1[kt], a1, 0, 0, 0);
            }
#pragma unroll
            for (int r = 0; r < 4; r++) {
                float v0 = fsilu(a0[r] + bb0);
                float v1 = fsilu(a1[r] + bb1);
                m2s[mt][r] = v0; m2s[mt][4 + r] = v1;
                float g = v0 * aw0 + v1 * aw1;
                g += __shfl_xor(g, 1, 64);
                g += __shfl_xor(g, 2, 64);
                g += __shfl_xor(g, 4, 64);
                g += __shfl_xor(g, 8, 64);
                if (lrow == 0) gpe[wv][mt * 16 + quad * 4 + r] = g;
            }
        }
    }
    __syncthreads();   // B2

    if (t < EPB) {
        sv_l[t]   = gpc[0][t] + gpc[1][t] + gpc[2][t] + gpc[3][t];
        gate_l[t] = fsigm(gpe[0][t] + gpe[1][t] + gpe[2][t] + gpe[3][t] + P.ab[0]);
    }
#pragma unroll
    for (int mt = 0; mt < 2; mt++)
#pragma unroll
        for (int r = 0; r < 4; r++) {
            const int erow = mt * 16 + quad * 4 + r;
            msg[erow * 132 + c0] = m2s[mt][r];
            msg[erow * 132 + c1] = m2s[mt][4 + r];
        }
    __syncthreads();   // B3

    if (t < 128) {
        const int col = t;
        float acc = 0.0f;
        int cur = dstl[0];
#pragma unroll 4
        for (int e = 0; e < EPB; e++) {
            const int d = dstl[e];
            if (d != cur) {
                atomAddF(&hne[(size_t)cur * 128 + col], acc);
                acc = 0.0f; cur = d;
            }
            acc += msg[e * 132 + col] * gate_l[e];
        }
        atomAddF(&hne[(size_t)cur * 128 + col], acc);
    } else if (t < 131) {
        const int ax = t - 128;
        float acc = 0.0f;
        int cur = dstl[0];
        for (int e = 0; e < EPB; e++) {
            const int d = dstl[e];
            if (d != cur) {
                atomAddF(&xne[cur * 3 + ax], acc);
                acc = 0.0f; cur = d;
            }
            acc += sv_l[e] * xdf[ax][e];
        }
        atomAddF(&xne[cur * 3 + ax], acc);
    }
}

// ---------------------------------------------------------------------------
// Node kernel: reads WS accumulators, writes d_out exactly once per element.
// ---------------------------------------------------------------------------
__global__ __launch_bounds__(256) void node_kernel(
    const float* __restrict__ h_lig, const float* __restrict__ zlig,
    const short* __restrict__ W1t, const float* __restrict__ b1v,
    const short* __restrict__ W2t, const float* __restrict__ b2v,
    const float* __restrict__ x_lig,
    const float* __restrict__ acc_h, const float* __restrict__ acc_x,
    float* __restrict__ h_out, float* __restrict__ x_out)
{
    __shared__ __align__(16) short f_lds[64 * FSTR];
    __shared__ __align__(16) short m_lds[64 * MSTR];
    const int t = threadIdx.x;
    const int nb = blockIdx.x * 64;

    {
        const int e = t >> 2, q = t & 3;
        const int node = nb + e;
        short* frow = &f_lds[e * FSTR + q * 32];
        if (node < 10000) {
            const float zi = frcp(zlig[node]);
            const float4* hp = (const float4*)(h_lig + (size_t)node * 128 + q * 32);
            const float4* np = (const float4*)(acc_h + (size_t)node * 128 + q * 32);
#pragma unroll
            for (int i = 0; i < 8; i++) {
                float4 v = hp[i];
                *(uint2*)(frow + i * 4) = make_uint2(pkbf(v.x, v.y), pkbf(v.z, v.w));
            }
#pragma unroll
            for (int i = 0; i < 8; i++) {
                float4 v = np[i];
                *(uint2*)(frow + 128 + i * 4) =
                    make_uint2(pkbf(v.x * zi, v.y * zi), pkbf(v.z * zi, v.w * zi));
            }
        } else {
            const uint2 zz = make_uint2(0, 0);
#pragma unroll
            for (int i = 0; i < 8; i++) {
                *(uint2*)(frow + i * 4) = zz;
                *(uint2*)(frow + 128 + i * 4) = zz;
            }
        }
    }
    __syncthreads();

    const int ln = t & 63, wv = t >> 6;
    const int lrow = ln & 15, quad = ln >> 4;
    const int c0 = wv * 32 + lrow, c1 = c0 + 16;

    {
        short8 bf0[8], bf1[8];
#pragma unroll
        for (int kt = 0; kt < 8; kt++) {
            bf0[kt] = *(const short8*)(W1t + c0 * 256 + kt * 32 + quad * 8);
            bf1[kt] = *(const short8*)(W1t + c1 * 256 + kt * 32 + quad * 8);
        }
        const float bb0 = b1v[c0], bb1 = b1v[c1];
#pragma unroll
        for (int mt = 0; mt < 4; mt++) {
            short8 af[8];
#pragma unroll
            for (int kt = 0; kt < 8; kt++)
                af[kt] = *(const short8*)(&f_lds[(mt * 16 + lrow) * FSTR + kt * 32 + quad * 8]);
            f32x4 a0 = {0.f, 0.f, 0.f, 0.f}, a1 = {0.f, 0.f, 0.f, 0.f};
#pragma unroll
            for (int kt = 0; kt < 8; kt++) {
                a0 = __builtin_amdgcn_mfma_f32_16x16x32_bf16(af[kt], bf0[kt], a0, 0, 0, 0);
                a1 = __builtin_amdgcn_mfma_f32_16x16x32_bf16(af[kt], bf1[kt], a1, 0, 0, 0);
            }
#pragma unroll
            for (int r = 0; r < 4; r++) {
                const int erow = mt * 16 + quad * 4 + r;
                m_lds[erow * MSTR + c0] = (short)f2bf(fsilu(a0[r] + bb0));
                m_lds[erow * MSTR + c1] = (short)f2bf(fsilu(a1[r] + bb1));
            }
        }
    }
    __syncthreads();

    {
        short8 bf0[4], bf1[4];
#pragma unroll
        for (int kt = 0; kt < 4; kt++) {
            bf0[kt] = *(const short8*)(W2t + c0 * 128 + kt * 32 + quad * 8);
            bf1[kt] = *(const short8*)(W2t + c1 * 128 + kt * 32 + quad * 8);
        }
        const float bb0 = b2v[c0], bb1 = b2v[c1];
#pragma unroll
        for (int mt = 0; mt < 4; mt++) {
            short8 af[4];
#pragma unroll
            for (int kt = 0; kt < 4; kt++)
                af[kt] = *(const short8*)(&m_lds[(mt * 16 + lrow) * MSTR + kt * 32 + quad * 8]);
            f32x4 a0 = {0.f, 0.f, 0.f, 0.f}, a1 = {0.f, 0.f, 0.f, 0.f};
#pragma unroll
            for (int kt = 0; kt < 4; kt++) {
                a0 = __builtin_amdgcn_mfma_f32_16x16x32_bf16(af[kt], bf0[kt], a0, 0, 0, 0);
                a1 = __builtin_amdgcn_mfma_f32_16x16x32_bf16(af[kt], bf1[kt], a1, 0, 0, 0);
            }
#pragma unroll
            for (int r = 0; r < 4; r++) {
                const int node = nb + mt * 16 + quad * 4 + r;
                if (node < 10000) {
                    h_out[(size_t)node * 128 + c0] = a0[r] + bb0 + h_lig[(size_t)node * 128 + c0];
                    h_out[(size_t)node * 128 + c1] = a1[r] + bb1 + h_lig[(size_t)node * 128 + c1];
                }
            }
        }
    }
    if (t < 64) {
        const int node = nb + t;
        if (node < 10000) {
            const float zi = frcp(zlig[node]);
#pragma unroll
            for (int i = 0; i < 3; i++)
                x_out[node * 3 + i] = x_lig[node * 3 + i] + acc_x[node * 3 + i] * zi;
        }
    }
}

extern "C" void kernel_launch(void* const* d_in, const int* in_sizes, int n_in,
                              void* d_out, int out_size, void* d_ws, size_t ws_size,
                              hipStream_t stream)
{
    (void)in_sizes; (void)n_in; (void)ws_size; (void)out_size;
    const float* h_lig  = (const float*)d_in[0];
    const float* h_kp   = (const float*)d_in[1];
    const float* x_lig  = (const float*)d_in[2];
    const float* x_kp   = (const float*)d_in[3];
    const float* z_lig  = (const float*)d_in[4];
    const float* ll_eW1 = (const float*)d_in[5];
    const float* ll_eb1 = (const float*)d_in[6];
    const float* ll_eW2 = (const float*)d_in[7];
    const float* ll_eb2 = (const float*)d_in[8];
    const float* ll_aW  = (const float*)d_in[9];
    const float* ll_ab  = (const float*)d_in[10];
    const float* ll_cW1 = (const float*)d_in[11];
    const float* ll_cb1 = (const float*)d_in[12];
    const float* ll_cW2 = (const float*)d_in[13];
    const float* ll_cb2 = (const float*)d_in[14];
    const float* ll_cW3 = (const float*)d_in[15];
    const float* kl_eW1 = (const float*)d_in[16];
    const float* kl_eb1 = (const float*)d_in[17];
    const float* kl_eW2 = (const float*)d_in[18];
    const float* kl_eb2 = (const float*)d_in[19];
    const float* kl_aW  = (const float*)d_in[20];
    const float* kl_ab  = (const float*)d_in[21];
    const float* kl_cW1 = (const float*)d_in[22];
    const float* kl_cb1 = (const float*)d_in[23];
    const float* kl_cW2 = (const float*)d_in[24];
    const float* kl_cb2 = (const float*)d_in[25];
    const float* kl_cW3 = (const float*)d_in[26];
    const float* n_W1   = (const float*)d_in[27];
    const float* n_b1   = (const float*)d_in[28];
    const float* n_W2   = (const float*)d_in[29];
    const float* n_b2   = (const float*)d_in[30];
    const int* ll_src = (const int*)d_in[31];
    const int* ll_dst = (const int*)d_in[32];
    const int* kl_src = (const int*)d_in[33];
    const int* kl_dst = (const int*)d_in[34];

    float* h_out = (float*)d_out;            // [10000,128]
    float* x_out = h_out + 1280000;          // [10000,3]

    // ws layout (bytes) — ~26.1 MB
    char* wsc = (char*)d_ws;
    short* wsb    = (short*)wsc;                 //       0: weights (491,520 B)
    short* P_ll_s = (short*)(wsc +   491520);    // 5,120,000 B  [10000][256]
    short* P_ll_d = (short*)(wsc +  5611520);    // 5,120,000 B
    short* P_kl_s = (short*)(wsc + 10731520);    // 1,024,000 B  [2000][256]
    short* P_kl_d = (short*)(wsc + 11755520);    // 5,120,000 B
    int* ll_ssrc  = (int*)(wsc + 16875520);      // 1,280,000 B
    int* ll_sdst  = (int*)(wsc + 18155520);      // 1,280,000 B
    int* kl_ssrc  = (int*)(wsc + 19435520);      //   640,000 B
    int* kl_sdst  = (int*)(wsc + 20075520);      //   640,000 B
    int* hist     = (int*)(wsc + 20715520);      //    80,000 B
    int* cursor   = (int*)(wsc + 20795520);      //    80,000 B
    float* hne    = (float*)(wsc + 20875520);    // 5,120,000 B  [10000][128]
    float* xne    = (float*)(wsc + 25995520);    //   120,000 B  [10000][3]

    ProjDesc pdv[8];
    pdv[0] = { h_lig, wsb + 0,      P_ll_s, ll_eb1, 10000, 0, 0,   0 };
    pdv[1] = { h_lig, wsb + 49152,  P_ll_s, ll_cb1, 10000, 0, 128, 0 };
    pdv[2] = { h_lig, wsb + 0,      P_ll_d, ll_eb1, 10000, 4, 0,   1 };
    pdv[3] = { h_lig, wsb + 49152,  P_ll_d, ll_cb1, 10000, 4, 128, 1 };
    pdv[4] = { h_kp,  wsb + 98304,  P_kl_s, kl_eb1,  2000, 0, 0,   0 };
    pdv[5] = { h_kp,  wsb + 147456, P_kl_s, kl_cb1,  2000, 0, 128, 0 };
    pdv[6] = { h_lig, wsb + 98304,  P_kl_d, kl_eb1, 10000, 4, 0,   1 };
    pdv[7] = { h_lig, wsb + 147456, P_kl_d, kl_cb1, 10000, 4, 128, 1 };

    // 1. zero hist (80 KB; hne/xne zeroed inside prep_hist)
    hipMemsetAsync(hist, 0, 80000, stream);

    // 2. zero accums + weight transpose + histogram
    {
        PrepArgs pa;
        pa.src[0] = ll_eW1; pa.src[1] = ll_eW2; pa.src[2] = ll_cW1; pa.src[3] = ll_cW2;
        pa.src[4] = kl_eW1; pa.src[5] = kl_eW2; pa.src[6] = kl_cW1; pa.src[7] = kl_cW2;
        pa.src[8] = n_W1;   pa.src[9] = n_W2;
        prep_hist_kernel<<<2835, 256, 0, stream>>>(pa, wsb, ll_dst, kl_dst, hist, hne);
    }
    // 3. scan (2 blocks) || proj[0..628)
    {
        SPArgs sp;
        sp.hist = hist; sp.cursor = cursor;
        for (int i = 0; i < 8; i++) sp.d[i] = pdv[i];
        scan_proj_kernel<<<2 + 628, 256, 0, stream>>>(sp);
    }
    // 4. scatter (1875 blocks) || proj[628..1256)
    {
        CArgs ca;
        ca.lls = ll_src; ca.lld = ll_dst; ca.kls = kl_src; ca.kld = kl_dst;
        ca.cursor = cursor;
        ca.ll_ssrc = ll_ssrc; ca.ll_sdst = ll_sdst;
        ca.kl_ssrc = kl_ssrc; ca.kl_sdst = kl_sdst;
        for (int i = 0; i < 8; i++) ca.d[i] = pdv[i];
        scatter_proj_kernel<<<1875 + 628, 256, 0, stream>>>(ca);
    }
    // 5. edges
    {
        EdgePair ep;
        ep.split = 10000;
        ep.s[0] = { P_ll_s, P_ll_d, x_lig, x_lig, ll_ssrc, ll_sdst,
                    ll_eW1 + 256 * 128, ll_cW1 + 256 * 128,
                    wsb + 32768, wsb + 81920, ll_eb2, ll_cb2,
                    ll_aW, ll_ab, ll_cW3 };
        ep.s[1] = { P_kl_s, P_kl_d, x_kp, x_lig, kl_ssrc, kl_sdst,
                    kl_eW1 + 256 * 128, kl_cW1 + 256 * 128,
                    wsb + 131072, wsb + 180224, kl_eb2, kl_cb2,
                    kl_aW, kl_ab, kl_cW3 };
        edge_kernel<<<15000, 256, 0, stream>>>(ep, hne, xne);
    }
    // 6. node MLP -> final outputs into d_out (write-once)
    node_kernel<<<157, 256, 0, stream>>>(
        h_lig, z_lig, wsb + 196608, n_b1, wsb + 229376, n_b2,
        x_lig, hne, xne, h_out, x_out);
}

// Round 13
// 399.178 us; speedup vs baseline: 2.0389x; 1.0296x over previous
//
#include <hip/hip_runtime.h>
#include <hip/hip_bf16.h>
#include <math.h>

#define EPB  32    // edges per block
#define MSTR 136   // m LDS row stride (shorts): 128 + 8 pad
#define FSTR 264   // node-kernel f stride

typedef __attribute__((ext_vector_type(8))) short short8;
typedef __attribute__((ext_vector_type(4))) float f32x4;

__device__ __forceinline__ unsigned short f2bf(float x) {
    unsigned int u = __float_as_uint(x);
    u += 0x7fffu + ((u >> 16) & 1u);   // round-to-nearest-even
    return (unsigned short)(u >> 16);
}
__device__ __forceinline__ float bf2f(short v) {
    return __uint_as_float(((unsigned int)(unsigned short)v) << 16);
}
__device__ __forceinline__ unsigned int pkbf(float a, float b) {
    __hip_bfloat162 h = __float22bfloat162_rn(make_float2(a, b));
    union { __hip_bfloat162 h2; unsigned int u; } cv; cv.h2 = h; return cv.u;
}
__device__ __forceinline__ float frcp(float x) { return __builtin_amdgcn_rcpf(x); }
__device__ __forceinline__ float fsilu(float x) {
    return x * frcp(1.0f + __expf(-x));
}
__device__ __forceinline__ float fsigm(float x) {
    return frcp(1.0f + __expf(-x));
}
__device__ __forceinline__ void atomAddF(float* p, float v) {
    unsafeAtomicAdd(p, v);   // hardware global_atomic_add_f32
}

// ---------------------------------------------------------------------------
// Kernel A: weight transpose (fp32 [K][128] -> bf16 [128][K]) + dst histogram
// ---------------------------------------------------------------------------
struct PrepArgs { const float* src[10]; };

__global__ __launch_bounds__(256) void prep_hist_kernel(PrepArgs pa, short* __restrict__ wsb,
                                                        const int* __restrict__ lld,
                                                        const int* __restrict__ kld,
                                                        int* __restrict__ hist) {
    int idx = blockIdx.x * 256 + threadIdx.x;
    if (idx < 245760) {
        int pair = idx / 49152;
        int rem  = idx - pair * 49152;
        int second = (rem >= 32768) ? 1 : 0;
        int mi = pair * 2 + second;
        int within = second ? (rem - 32768) : rem;
        int n, k, K;
        if (second) { K = 128; n = within >> 7; k = within & 127; }
        else        { K = 256; n = within >> 8; k = within & 255; }
        int dstoff = pair * 49152 + second * 32768;
        wsb[dstoff + n * K + k] = (short)f2bf(pa.src[mi][k * 128 + n]);
        return;
    }
    idx -= 245760;
    if (idx < 320000) { atomicAdd(&hist[lld[idx]], 1); return; }
    idx -= 320000;
    if (idx < 160000) atomicAdd(&hist[10000 + kld[idx]], 1);
}

// ---------------------------------------------------------------------------
// Kernel B: exclusive scan of 10000 bins per edge type (LDS-staged)
// ---------------------------------------------------------------------------
__global__ __launch_bounds__(256) void scan_kernel(const int* __restrict__ hist,
                                                   int* __restrict__ cursor) {
    __shared__ int bins[10000];
    __shared__ int ps[256];
    const int b = blockIdx.x, t = threadIdx.x;
    const int* h = hist + b * 10000;
    int* cur = cursor + b * 10000;
    for (int i = t; i < 10000; i += 256) bins[i] = h[i];
    __syncthreads();
    const int base = t * 40;
    int s = 0;
#pragma unroll 8
    for (int i = 0; i < 40; i++) { int ii = base + i; if (ii < 10000) s += bins[ii]; }
    ps[t] = s;
    __syncthreads();
    for (int off = 1; off < 256; off <<= 1) {
        int v = (t >= off) ? ps[t - off] : 0;
        __syncthreads();
        ps[t] += v;
        __syncthreads();
    }
    int run = ps[t] - s;   // exclusive prefix of this chunk
    for (int i = 0; i < 40; i++) {
        int ii = base + i;
        if (ii < 10000) { int c = bins[ii]; bins[ii] = run; run += c; }
    }
    __syncthreads();
    for (int i = t; i < 10000; i += 256) cur[i] = bins[i];
}

// ---------------------------------------------------------------------------
// Kernel C: fused scatter (blocks 0..1874) + projection GEMMs (blocks 1875..)
// ---------------------------------------------------------------------------
struct ProjDesc { const float* A; const short* Bt; short* out; const float* bias;
                  int rows; int ktb; int co; int hasb; };
struct CArgs {
    const int *lls, *lld, *kls, *kld;
    int* cursor;
    int *ll_ssrc, *ll_sdst, *kl_ssrc, *kl_sdst;
    ProjDesc d[8];
};

__global__ __launch_bounds__(256) void scatter_proj_kernel(CArgs ca) {
    __shared__ __align__(16) short a_lds[64 * MSTR];
    const int t = threadIdx.x;
    if (blockIdx.x < 1875) {
        int i = blockIdx.x * 256 + t;
        if (i < 320000) {
            int d = ca.lld[i];
            int p = atomicAdd(&ca.cursor[d], 1);
            ca.ll_ssrc[p] = ca.lls[i]; ca.ll_sdst[p] = d;
        } else if (i < 480000) {
            int j = i - 320000;
            int d = ca.kld[j];
            int p = atomicAdd(&ca.cursor[10000 + d], 1);
            ca.kl_ssrc[p] = ca.kls[j]; ca.kl_sdst[p] = d;
        }
        return;
    }
    const int pb = blockIdx.x - 1875;
    const int di = pb / 157, tile = pb - di * 157;
    const ProjDesc pd = ca.d[di];
    if (tile * 64 >= pd.rows) return;
    {
        const int r = t >> 2, q = t & 3;
        const int node = tile * 64 + r;
        short* arow = a_lds + r * MSTR + q * 32;
        if (node < pd.rows) {
            const float* ap = pd.A + (size_t)node * 128 + q * 32;
#pragma unroll
            for (int i = 0; i < 4; i++) {
                float4 v0 = *(const float4*)(ap + i * 8);
                float4 v1 = *(const float4*)(ap + i * 8 + 4);
                uint4 o;
                o.x = pkbf(v0.x, v0.y); o.y = pkbf(v0.z, v0.w);
                o.z = pkbf(v1.x, v1.y); o.w = pkbf(v1.z, v1.w);
                *(uint4*)(arow + i * 8) = o;
            }
        } else {
            uint4 z = make_uint4(0, 0, 0, 0);
#pragma unroll
            for (int i = 0; i < 4; i++) *(uint4*)(arow + i * 8) = z;
        }
    }
    __syncthreads();

    const int ln = t & 63, wv = t >> 6;
    const int lrow = ln & 15, quad = ln >> 4;
    const int c0 = wv * 32 + lrow, c1 = c0 + 16;

    short8 bf0[4], bf1[4];
#pragma unroll
    for (int kt = 0; kt < 4; kt++) {
        bf0[kt] = *(const short8*)(pd.Bt + c0 * 256 + (pd.ktb + kt) * 32 + quad * 8);
        bf1[kt] = *(const short8*)(pd.Bt + c1 * 256 + (pd.ktb + kt) * 32 + quad * 8);
    }
    const float bb0 = pd.hasb ? pd.bias[c0] : 0.0f;
    const float bb1 = pd.hasb ? pd.bias[c1] : 0.0f;
#pragma unroll
    for (int mt = 0; mt < 4; mt++) {
        short8 af[4];
#pragma unroll
        for (int kt = 0; kt < 4; kt++)
            af[kt] = *(const short8*)(&a_lds[(mt * 16 + lrow) * MSTR + kt * 32 + quad * 8]);
        f32x4 a0 = {0.f, 0.f, 0.f, 0.f}, a1 = {0.f, 0.f, 0.f, 0.f};
#pragma unroll
        for (int kt = 0; kt < 4; kt++) {
            a0 = __builtin_amdgcn_mfma_f32_16x16x32_bf16(af[kt], bf0[kt], a0, 0, 0, 0);
            a1 = __builtin_amdgcn_mfma_f32_16x16x32_bf16(af[kt], bf1[kt], a1, 0, 0, 0);
        }
#pragma unroll
        for (int r = 0; r < 4; r++) {
            const int node = tile * 64 + mt * 16 + quad * 4 + r;
            if (node < pd.rows) {
                pd.out[(size_t)node * 256 + pd.co + c0] = (short)f2bf(a0[r] + bb0);
                pd.out[(size_t)node * 256 + pd.co + c1] = (short)f2bf(a1[r] + bb1);
            }
        }
    }
}

// ---------------------------------------------------------------------------
// Edge kernel: EPB=32, 4 waves, 3 barriers, fast-rcp silu, XCD-aware swizzle.
// Consecutive hardware blocks are distributed round-robin over 8 XCDs; we map
// them to far-apart chunks of the dst-sorted edge list so each XCD's L2 holds
// a contiguous ~640 KB slice of Pd + its hne atomic range (speed-only hint).
// ---------------------------------------------------------------------------
struct EdgeSet {
    const short *Ps, *Pd;        // [nodes][256] bf16: 0..127 e-proj, 128..255 c-proj (b1 in Pd)
    const float *xs, *xd;
    const int *esrc, *edst;      // dst-sorted
    const float *w256e, *w256c;  // dij coefficient rows (fp32)
    const short *W2t, *cW2t;     // [128][128] bf16 [col][k]
    const float *b2e, *b2c;
    const float *aW, *ab, *cW3;
};
struct EdgePair { EdgeSet s[2]; int split; };

__global__ __launch_bounds__(256, 8) void edge_kernel(EdgePair ep,
                                                      float* __restrict__ hne,
                                                      float* __restrict__ xne)
{
    __shared__ __align__(16) char mbuf[EPB * MSTR * 4];  // 17408: mh|mc bf16, overlay msg f32
    __shared__ float sv_l[EPB];
    __shared__ float gate_l[EPB];
    __shared__ float xdf[3][EPB];
    __shared__ int   dstl[EPB];
    __shared__ float gpc[4][EPB];
    __shared__ float gpe[4][EPB];

    short* mh = (short*)mbuf;
    short* mc = (short*)(mbuf + EPB * MSTR * 2);
    float* msg = (float*)mbuf;          // stride 132 floats, overlays mh+mc after GEMMs

    const int isKL = (blockIdx.x >= ep.split) ? 1 : 0;
    const EdgeSet P = ep.s[isKL];
    int b = blockIdx.x - (isKL ? ep.split : 0);
    // XCD swizzle: 10000 ll blocks = 8 x 1250, 5000 kl blocks = 8 x 625.
    const int nb8 = isKL ? 625 : 1250;
    b = (b & 7) * nb8 + (b >> 3);
    const int eb = b * EPB;
    const int t = threadIdx.x;

    // ---- phase 0: gather projections, fuse add+dij*w+silu, pack bf16 ----
    {
        const int e = t >> 3, q = t & 7;     // 8 threads/edge, 16 cols each
        const int eid = eb + e;
        const int s = P.esrc[eid], d = P.edst[eid];
        float dx = P.xs[s * 3 + 0] - P.xd[d * 3 + 0];
        float dy = P.xs[s * 3 + 1] - P.xd[d * 3 + 1];
        float dz = P.xs[s * 3 + 2] - P.xd[d * 3 + 2];
        float dd = __builtin_amdgcn_sqrtf(dx * dx + dy * dy + dz * dz);
        if (q == 0) {
            dstl[e] = d;
            float inv = frcp(dd + 1.0f);
            xdf[0][e] = dx * inv; xdf[1][e] = dy * inv; xdf[2][e] = dz * inv;
        }
        const short* psrow = P.Ps + (size_t)s * 256 + q * 16;
        const short* pdrow = P.Pd + (size_t)d * 256 + q * 16;
#pragma unroll
        for (int path = 0; path < 2; path++) {
            const short* ps = psrow + path * 128;
            const short* pq = pdrow + path * 128;
            const float* wq = (path ? P.w256c : P.w256e) + q * 16;
            short* mrow = (path ? mc : mh) + e * MSTR + q * 16;
#pragma unroll
            for (int i = 0; i < 2; i++) {
                short8 a = *(const short8*)(ps + i * 8);
                short8 b2 = *(const short8*)(pq + i * 8);
                float4 wA = *(const float4*)(wq + i * 8);
                float4 wB = *(const float4*)(wq + i * 8 + 4);
                float v0 = fsilu(bf2f(a[0]) + bf2f(b2[0]) + dd * wA.x);
                float v1 = fsilu(bf2f(a[1]) + bf2f(b2[1]) + dd * wA.y);
                float v2 = fsilu(bf2f(a[2]) + bf2f(b2[2]) + dd * wA.z);
                float v3 = fsilu(bf2f(a[3]) + bf2f(b2[3]) + dd * wA.w);
                float v4 = fsilu(bf2f(a[4]) + bf2f(b2[4]) + dd * wB.x);
                float v5 = fsilu(bf2f(a[5]) + bf2f(b2[5]) + dd * wB.y);
                float v6 = fsilu(bf2f(a[6]) + bf2f(b2[6]) + dd * wB.z);
                float v7 = fsilu(bf2f(a[7]) + bf2f(b2[7]) + dd * wB.w);
                uint4 o;
                o.x = pkbf(v0, v1); o.y = pkbf(v2, v3);
                o.z = pkbf(v4, v5); o.w = pkbf(v6, v7);
                *(uint4*)(mrow + i * 8) = o;
            }
        }
    }
    __syncthreads();   // B1

    const int ln = t & 63, wv = t >> 6;
    const int lrow = ln & 15, quad = ln >> 4;
    const int c0 = wv * 32 + lrow, c1 = c0 + 16;

    // ---- GEMM2c: c2 = silu(m_c @ cW2 + cb2); sv partials -> gpc ----
    {
        short8 bf0[4], bf1[4];
#pragma unroll
        for (int kt = 0; kt < 4; kt++) {
            bf0[kt] = *(const short8*)(P.cW2t + c0 * 128 + kt * 32 + quad * 8);
            bf1[kt] = *(const short8*)(P.cW2t + c1 * 128 + kt * 32 + quad * 8);
        }
        const float cw0 = P.cW3[c0], cw1 = P.cW3[c1];
        const float bb0 = P.b2c[c0], bb1 = P.b2c[c1];
#pragma unroll
        for (int mt = 0; mt < 2; mt++) {
            short8 af[4];
#pragma unroll
            for (int kt = 0; kt < 4; kt++)
                af[kt] = *(const short8*)(&mc[(mt * 16 + lrow) * MSTR + kt * 32 + quad * 8]);
            f32x4 a0 = {0.f, 0.f, 0.f, 0.f}, a1 = {0.f, 0.f, 0.f, 0.f};
#pragma unroll
            for (int kt = 0; kt < 4; kt++) {
                a0 = __builtin_amdgcn_mfma_f32_16x16x32_bf16(af[kt], bf0[kt], a0, 0, 0, 0);
                a1 = __builtin_amdgcn_mfma_f32_16x16x32_bf16(af[kt], bf1[kt], a1, 0, 0, 0);
            }
#pragma unroll
            for (int r = 0; r < 4; r++) {
                float v0 = fsilu(a0[r] + bb0);
                float v1 = fsilu(a1[r] + bb1);
                float g = v0 * cw0 + v1 * cw1;
                g += __shfl_xor(g, 1, 64);
                g += __shfl_xor(g, 2, 64);
                g += __shfl_xor(g, 4, 64);
                g += __shfl_xor(g, 8, 64);
                if (lrow == 0) gpc[wv][mt * 16 + quad * 4 + r] = g;
            }
        }
    }

    // ---- GEMM2e: m2 = silu(m_h @ eW2 + b2); gate partials -> gpe; m2 in regs ----
    float m2s[2][8];
    {
        short8 bf0[4], bf1[4];
#pragma unroll
        for (int kt = 0; kt < 4; kt++) {
            bf0[kt] = *(const short8*)(P.W2t + c0 * 128 + kt * 32 + quad * 8);
            bf1[kt] = *(const short8*)(P.W2t + c1 * 128 + kt * 32 + quad * 8);
        }
        const float aw0 = P.aW[c0], aw1 = P.aW[c1];
        const float bb0 = P.b2e[c0], bb1 = P.b2e[c1];
#pragma unroll
        for (int mt = 0; mt < 2; mt++) {
            short8 af[4];
#pragma unroll
            for (int kt = 0; kt < 4; kt++)
                af[kt] = *(const short8*)(&mh[(mt * 16 + lrow) * MSTR + kt * 32 + quad * 8]);
            f32x4 a0 = {0.f, 0.f, 0.f, 0.f}, a1 = {0.f, 0.f, 0.f, 0.f};
#pragma unroll
            for (int kt = 0; kt < 4; kt++) {
                a0 = __builtin_amdgcn_mfma_f32_16x16x32_bf16(af[kt], bf0[kt], a0, 0, 0, 0);
                a1 = __builtin_amdgcn_mfma_f32_16x16x32_bf16(af[kt], bf1[kt], a1, 0, 0, 0);
            }
#pragma unroll
            for (int r = 0; r < 4; r++) {
                float v0 = fsilu(a0[r] + bb0);
                float v1 = fsilu(a1[r] + bb1);
                m2s[mt][r] = v0; m2s[mt][4 + r] = v1;
                float g = v0 * aw0 + v1 * aw1;
                g += __shfl_xor(g, 1, 64);
                g += __shfl_xor(g, 2, 64);
                g += __shfl_xor(g, 4, 64);
                g += __shfl_xor(g, 8, 64);
                if (lrow == 0) gpe[wv][mt * 16 + quad * 4 + r] = g;
            }
        }
    }
    __syncthreads();   // B2 (mh/mc reads done -> msg overlay safe; gpc/gpe complete)

    if (t < EPB) {
        sv_l[t]   = gpc[0][t] + gpc[1][t] + gpc[2][t] + gpc[3][t];
        gate_l[t] = fsigm(gpe[0][t] + gpe[1][t] + gpe[2][t] + gpe[3][t] + P.ab[0]);
    }
#pragma unroll
    for (int mt = 0; mt < 2; mt++)
#pragma unroll
        for (int r = 0; r < 4; r++) {
            const int erow = mt * 16 + quad * 4 + r;
            msg[erow * 132 + c0] = m2s[mt][r];
            msg[erow * 132 + c1] = m2s[mt][4 + r];
        }
    __syncthreads();   // B3 (last barrier)

    // ---- segmented reductions (dst-sorted); gate folded into h-scan ----
    if (t < 128) {
        const int col = t;
        float acc = 0.0f;
        int cur = dstl[0];
#pragma unroll 4
        for (int e = 0; e < EPB; e++) {
            const int d = dstl[e];
            if (d != cur) {
                atomAddF(&hne[(size_t)cur * 128 + col], acc);
                acc = 0.0f; cur = d;
            }
            acc += msg[e * 132 + col] * gate_l[e];
        }
        atomAddF(&hne[(size_t)cur * 128 + col], acc);
    } else if (t < 131) {
        const int ax = t - 128;
        float acc = 0.0f;
        int cur = dstl[0];
        for (int e = 0; e < EPB; e++) {
            const int d = dstl[e];
            if (d != cur) {
                atomAddF(&xne[cur * 3 + ax], acc);
                acc = 0.0f; cur = d;
            }
            acc += sv_l[e] * xdf[ax][e];
        }
        atomAddF(&xne[cur * 3 + ax], acc);
    }
}

// ---------------------------------------------------------------------------
// Node kernel: reads WS accumulators, writes d_out exactly once per element.
// ---------------------------------------------------------------------------
__global__ __launch_bounds__(256) void node_kernel(
    const float* __restrict__ h_lig, const float* __restrict__ zlig,
    const short* __restrict__ W1t, const float* __restrict__ b1v,
    const short* __restrict__ W2t, const float* __restrict__ b2v,
    const float* __restrict__ x_lig,
    const float* __restrict__ acc_h, const float* __restrict__ acc_x,
    float* __restrict__ h_out, float* __restrict__ x_out)
{
    __shared__ __align__(16) short f_lds[64 * FSTR];
    __shared__ __align__(16) short m_lds[64 * MSTR];
    const int t = threadIdx.x;
    const int nb = blockIdx.x * 64;

    {
        const int e = t >> 2, q = t & 3;
        const int node = nb + e;
        short* frow = &f_lds[e * FSTR + q * 32];
        if (node < 10000) {
            const float zi = frcp(zlig[node]);
            const float4* hp = (const float4*)(h_lig + (size_t)node * 128 + q * 32);
            const float4* np = (const float4*)(acc_h + (size_t)node * 128 + q * 32);
#pragma unroll
            for (int i = 0; i < 8; i++) {
                float4 v = hp[i];
                *(uint2*)(frow + i * 4) = make_uint2(pkbf(v.x, v.y), pkbf(v.z, v.w));
            }
#pragma unroll
            for (int i = 0; i < 8; i++) {
                float4 v = np[i];
                *(uint2*)(frow + 128 + i * 4) =
                    make_uint2(pkbf(v.x * zi, v.y * zi), pkbf(v.z * zi, v.w * zi));
            }
        } else {
            const uint2 zz = make_uint2(0, 0);
#pragma unroll
            for (int i = 0; i < 8; i++) {
                *(uint2*)(frow + i * 4) = zz;
                *(uint2*)(frow + 128 + i * 4) = zz;
            }
        }
    }
    __syncthreads();

    const int ln = t & 63, wv = t >> 6;
    const int lrow = ln & 15, quad = ln >> 4;
    const int c0 = wv * 32 + lrow, c1 = c0 + 16;

    {
        short8 bf0[8], bf1[8];
#pragma unroll
        for (int kt = 0; kt < 8; kt++) {
            bf0[kt] = *(const short8*)(W1t + c0 * 256 + kt * 32 + quad * 8);
            bf1[kt] = *(const short8*)(W1t + c1 * 256 + kt * 32 + quad * 8);
        }
        const float bb0 = b1v[c0], bb1 = b1v[c1];
#pragma unroll
        for (int mt = 0; mt < 4; mt++) {
            short8 af[8];
#pragma unroll
            for (int kt = 0; kt < 8; kt++)
                af[kt] = *(const short8*)(&f_lds[(mt * 16 + lrow) * FSTR + kt * 32 + quad * 8]);
            f32x4 a0 = {0.f, 0.f, 0.f, 0.f}, a1 = {0.f, 0.f, 0.f, 0.f};
#pragma unroll
            for (int kt = 0; kt < 8; kt++) {
                a0 = __builtin_amdgcn_mfma_f32_16x16x32_bf16(af[kt], bf0[kt], a0, 0, 0, 0);
                a1 = __builtin_amdgcn_mfma_f32_16x16x32_bf16(af[kt], bf1[kt], a1, 0, 0, 0);
            }
#pragma unroll
            for (int r = 0; r < 4; r++) {
                const int erow = mt * 16 + quad * 4 + r;
                m_lds[erow * MSTR + c0] = (short)f2bf(fsilu(a0[r] + bb0));
                m_lds[erow * MSTR + c1] = (short)f2bf(fsilu(a1[r] + bb1));
            }
        }
    }
    __syncthreads();

    {
        short8 bf0[4], bf1[4];
#pragma unroll
        for (int kt = 0; kt < 4; kt++) {
            bf0[kt] = *(const short8*)(W2t + c0 * 128 + kt * 32 + quad * 8);
            bf1[kt] = *(const short8*)(W2t + c1 * 128 + kt * 32 + quad * 8);
        }
        const float bb0 = b2v[c0], bb1 = b2v[c1];
#pragma unroll
        for (int mt = 0; mt < 4; mt++) {
            short8 af[4];
#pragma unroll
            for (int kt = 0; kt < 4; kt++)
                af[kt] = *(const short8*)(&m_lds[(mt * 16 + lrow) * MSTR + kt * 32 + quad * 8]);
            f32x4 a0 = {0.f, 0.f, 0.f, 0.f}, a1 = {0.f, 0.f, 0.f, 0.f};
#pragma unroll
            for (int kt = 0; kt < 4; kt++) {
                a0 = __builtin_amdgcn_mfma_f32_16x16x32_bf16(af[kt], bf0[kt], a0, 0, 0, 0);
                a1 = __builtin_amdgcn_mfma_f32_16x16x32_bf16(af[kt], bf1[kt], a1, 0, 0, 0);
            }
#pragma unroll
            for (int r = 0; r < 4; r++) {
                const int node = nb + mt * 16 + quad * 4 + r;
                if (node < 10000) {
                    h_out[(size_t)node * 128 + c0] = a0[r] + bb0 + h_lig[(size_t)node * 128 + c0];
                    h_out[(size_t)node * 128 + c1] = a1[r] + bb1 + h_lig[(size_t)node * 128 + c1];
                }
            }
        }
    }
    if (t < 64) {
        const int node = nb + t;
        if (node < 10000) {
            const float zi = frcp(zlig[node]);
#pragma unroll
            for (int i = 0; i < 3; i++)
                x_out[node * 3 + i] = x_lig[node * 3 + i] + acc_x[node * 3 + i] * zi;
        }
    }
}

extern "C" void kernel_launch(void* const* d_in, const int* in_sizes, int n_in,
                              void* d_out, int out_size, void* d_ws, size_t ws_size,
                              hipStream_t stream)
{
    (void)in_sizes; (void)n_in; (void)ws_size; (void)out_size;
    const float* h_lig  = (const float*)d_in[0];
    const float* h_kp   = (const float*)d_in[1];
    const float* x_lig  = (const float*)d_in[2];
    const float* x_kp   = (const float*)d_in[3];
    const float* z_lig  = (const float*)d_in[4];
    const float* ll_eW1 = (const float*)d_in[5];
    const float* ll_eb1 = (const float*)d_in[6];
    const float* ll_eW2 = (const float*)d_in[7];
    const float* ll_eb2 = (const float*)d_in[8];
    const float* ll_aW  = (const float*)d_in[9];
    const float* ll_ab  = (const float*)d_in[10];
    const float* ll_cW1 = (const float*)d_in[11];
    const float* ll_cb1 = (const float*)d_in[12];
    const float* ll_cW2 = (const float*)d_in[13];
    const float* ll_cb2 = (const float*)d_in[14];
    const float* ll_cW3 = (const float*)d_in[15];
    const float* kl_eW1 = (const float*)d_in[16];
    const float* kl_eb1 = (const float*)d_in[17];
    const float* kl_eW2 = (const float*)d_in[18];
    const float* kl_eb2 = (const float*)d_in[19];
    const float* kl_aW  = (const float*)d_in[20];
    const float* kl_ab  = (const float*)d_in[21];
    const float* kl_cW1 = (const float*)d_in[22];
    const float* kl_cb1 = (const float*)d_in[23];
    const float* kl_cW2 = (const float*)d_in[24];
    const float* kl_cb2 = (const float*)d_in[25];
    const float* kl_cW3 = (const float*)d_in[26];
    const float* n_W1   = (const float*)d_in[27];
    const float* n_b1   = (const float*)d_in[28];
    const float* n_W2   = (const float*)d_in[29];
    const float* n_b2   = (const float*)d_in[30];
    const int* ll_src = (const int*)d_in[31];
    const int* ll_dst = (const int*)d_in[32];
    const int* kl_src = (const int*)d_in[33];
    const int* kl_dst = (const int*)d_in[34];

    float* h_out = (float*)d_out;            // [10000,128]
    float* x_out = h_out + 1280000;          // [10000,3]

    // ws layout (bytes) — ~26.1 MB; accumulators live in WS (d_out write-once)
    char* wsc = (char*)d_ws;
    short* wsb    = (short*)wsc;                 //       0: weights (491,520 B)
    short* P_ll_s = (short*)(wsc +   491520);    // 5,120,000 B  [10000][256]
    short* P_ll_d = (short*)(wsc +  5611520);    // 5,120,000 B
    short* P_kl_s = (short*)(wsc + 10731520);    // 1,024,000 B  [2000][256]
    short* P_kl_d = (short*)(wsc + 11755520);    // 5,120,000 B
    int* ll_ssrc  = (int*)(wsc + 16875520);      // 1,280,000 B
    int* ll_sdst  = (int*)(wsc + 18155520);      // 1,280,000 B
    int* kl_ssrc  = (int*)(wsc + 19435520);      //   640,000 B
    int* kl_sdst  = (int*)(wsc + 20075520);      //   640,000 B
    int* hist     = (int*)(wsc + 20715520);      //    80,000 B (20000 ints)
    int* cursor   = (int*)(wsc + 20795520);      //    80,000 B
    float* hne    = (float*)(wsc + 20875520);    // 5,120,000 B  [10000][128]
    float* xne    = (float*)(wsc + 25995520);    //   120,000 B  [10000][3] -> end 26,115,520

    hipMemsetAsync(hne, 0, 5240000, stream);     // hne + xne (contiguous)
    hipMemsetAsync(hist, 0, 80000, stream);

    // A. weight transpose + histogram
    {
        PrepArgs pa;
        pa.src[0] = ll_eW1; pa.src[1] = ll_eW2; pa.src[2] = ll_cW1; pa.src[3] = ll_cW2;
        pa.src[4] = kl_eW1; pa.src[5] = kl_eW2; pa.src[6] = kl_cW1; pa.src[7] = kl_cW2;
        pa.src[8] = n_W1;   pa.src[9] = n_W2;
        prep_hist_kernel<<<2835, 256, 0, stream>>>(pa, wsb, ll_dst, kl_dst, hist);
    }
    // B. scan
    scan_kernel<<<2, 256, 0, stream>>>(hist, cursor);
    // C. scatter + projections fused
    {
        CArgs ca;
        ca.lls = ll_src; ca.lld = ll_dst; ca.kls = kl_src; ca.kld = kl_dst;
        ca.cursor = cursor;
        ca.ll_ssrc = ll_ssrc; ca.ll_sdst = ll_sdst;
        ca.kl_ssrc = kl_ssrc; ca.kl_sdst = kl_sdst;
        ca.d[0] = { h_lig, wsb + 0,      P_ll_s, ll_eb1, 10000, 0, 0,   0 };
        ca.d[1] = { h_lig, wsb + 49152,  P_ll_s, ll_cb1, 10000, 0, 128, 0 };
        ca.d[2] = { h_lig, wsb + 0,      P_ll_d, ll_eb1, 10000, 4, 0,   1 };
        ca.d[3] = { h_lig, wsb + 49152,  P_ll_d, ll_cb1, 10000, 4, 128, 1 };
        ca.d[4] = { h_kp,  wsb + 98304,  P_kl_s, kl_eb1,  2000, 0, 0,   0 };
        ca.d[5] = { h_kp,  wsb + 147456, P_kl_s, kl_cb1,  2000, 0, 128, 0 };
        ca.d[6] = { h_lig, wsb + 98304,  P_kl_d, kl_eb1, 10000, 4, 0,   1 };
        ca.d[7] = { h_lig, wsb + 147456, P_kl_d, kl_cb1, 10000, 4, 128, 1 };
        scatter_proj_kernel<<<1875 + 8 * 157, 256, 0, stream>>>(ca);
    }
    // D. edges (ll + kl in one launch), EPB=32, XCD-swizzled
    {
        EdgePair ep;
        ep.split = 10000;
        ep.s[0] = { P_ll_s, P_ll_d, x_lig, x_lig, ll_ssrc, ll_sdst,
                    ll_eW1 + 256 * 128, ll_cW1 + 256 * 128,
                    wsb + 32768, wsb + 81920, ll_eb2, ll_cb2,
                    ll_aW, ll_ab, ll_cW3 };
        ep.s[1] = { P_kl_s, P_kl_d, x_kp, x_lig, kl_ssrc, kl_sdst,
                    kl_eW1 + 256 * 128, kl_cW1 + 256 * 128,
                    wsb + 131072, wsb + 180224, kl_eb2, kl_cb2,
                    kl_aW, kl_ab, kl_cW3 };
        edge_kernel<<<15000, 256, 0, stream>>>(ep, hne, xne);
    }
    // E. node MLP -> final outputs into d_out (write-once)
    node_kernel<<<157, 256, 0, stream>>>(
        h_lig, z_lig, wsb + 196608, n_b1, wsb + 229376, n_b2,
        x_lig, hne, xne, h_out, x_out);
}